// Round 2
// baseline (510.888 us; speedup 1.0000x reference)
//
#include <hip/hip_runtime.h>

// ---------------- constants ----------------
// B=8, C=32, CO=32, NIN=16, NOUT=10, D1=D2=512, NRC=1344
// outputs (fp32, concatenated): zw0[8,32,512,16] zw1[8,32,512,512] zw2[8,32,10,512]
//                               u0[8,32,512] u1[8,32,512] u2[8,32,10]
#define OUT_ZW1 2097152u
#define OUT_ZW2 69206016u
#define OUT_U0  70516736u
#define OUT_U1  70647808u
#define OUT_U2  70778880u

// workspace layout (floats) — ~13.3 MB total
#define WS_RM1      0u
#define WS_CM1      131072u
#define WS_CM0      262144u
#define WS_RM2      393216u
#define WS_CM2      524288u
#define WS_RC       526848u
#define WS_TW0      537600u
#define WS_TB0      541696u
#define WS_TL1      541952u
#define WS_TBIAS1   542208u
#define WS_TFIN     542464u
#define WS_RTERM    545024u
#define WS_CTERM    676096u
#define WS_W0T      807168u
#define WS_WT_RPT   2904320u
#define WS_WT_B0    3199232u
#define WS_WT_FIN   3217664u
#define WS_WT_L1    3330304u

static __device__ __forceinline__ float wave_reduce(float v) {
#pragma unroll
  for (int off = 32; off > 0; off >>= 1) v += __shfl_down(v, off);
  return v;
}

// zero ONLY the atomic-accumulated regions: rm1 [131072] and rc [10752].
// (rocclr fillBufferAligned took 164us for this — 1/3 of total runtime.)
__global__ __launch_bounds__(256) void kzero(float* __restrict__ ws) {
  int i = blockIdx.x * 256 + threadIdx.x;
  if (i < 131072) ws[WS_RM1 + i] = 0.f;
  else if (i < 131072 + 10752) ws[WS_RC + (i - 131072)] = 0.f;
}

__global__ void ktrans(const float* __restrict__ A, float* __restrict__ At, int R, int C) {
  int idx = blockIdx.x * 256 + threadIdx.x;
  if (idx >= R * C) return;
  int r = idx / C, c = idx - r * C;
  At[(size_t)c * R + r] = A[idx];
}

__global__ __launch_bounds__(256) void ktransw0(const float* __restrict__ w0,
                                                float* __restrict__ w0T) {
  int bc = blockIdx.x;
  int b = bc >> 5, c = bc & 31;
  for (int k = 0; k < 16; ++k)
    for (int d = threadIdx.x; d < 512; d += 256)
      w0T[((size_t)(b * 512 + c * 16 + k)) * 512 + d] = w0[((size_t)bc * 512 + d) * 16 + k];
}

__global__ __launch_bounds__(256) void kstats(
    const float* __restrict__ w0, const float* __restrict__ w2,
    const float* __restrict__ b0, const float* __restrict__ b1,
    const float* __restrict__ b2, float* __restrict__ cm0, float* __restrict__ rm2,
    float* __restrict__ cm2, float* __restrict__ rc) {
  int bc = blockIdx.x;
  int b = bc >> 5, c = bc & 31;
  int tid = threadIdx.x, lane = tid & 63;
  __shared__ float sred[16];
  __shared__ float stot;
  float* rcb = rc + b * 1344;

  if (tid < 16) sred[tid] = 0.f;
  if (tid == 0) stot = 0.f;
  __syncthreads();
  {
    float rm0p[16];
#pragma unroll
    for (int k = 0; k < 16; ++k) rm0p[k] = 0.f;
    float tot = 0.f;
    for (int d = tid; d < 512; d += 256) {
      const float4* p = (const float4*)(w0 + ((size_t)bc * 512 + d) * 16);
      float s = 0.f;
#pragma unroll
      for (int q = 0; q < 4; ++q) {
        float4 v = p[q];
        s += v.x + v.y + v.z + v.w;
        rm0p[q * 4 + 0] += v.x; rm0p[q * 4 + 1] += v.y;
        rm0p[q * 4 + 2] += v.z; rm0p[q * 4 + 3] += v.w;
      }
      cm0[(size_t)bc * 512 + d] = s * (1.f / 16.f);
      tot += s;
    }
#pragma unroll
    for (int k = 0; k < 16; ++k) {
      float r = wave_reduce(rm0p[k]);
      if (lane == 0) atomicAdd(&sred[k], r);
    }
    float rt = wave_reduce(tot);
    if (lane == 0) atomicAdd(&stot, rt);
  }
  __syncthreads();
  if (tid < 16) rcb[192 + c * 16 + tid] = sred[tid] * (1.f / 512.f);
  if (tid == 0) rcb[c] = stot * (1.f / 8192.f);
  __syncthreads();

  if (tid < 10) sred[tid] = 0.f;
  if (tid == 0) stot = 0.f;
  __syncthreads();
  {
    float cm2p[10];
#pragma unroll
    for (int k = 0; k < 10; ++k) cm2p[k] = 0.f;
    float tot = 0.f;
    for (int d = tid; d < 512; d += 256) {
      float s = 0.f;
#pragma unroll
      for (int k = 0; k < 10; ++k) {
        float v = w2[((size_t)bc * 10 + k) * 512 + d];
        s += v; cm2p[k] += v;
      }
      rm2[(size_t)bc * 512 + d] = s * 0.1f;
      tot += s;
    }
#pragma unroll
    for (int k = 0; k < 10; ++k) {
      float r = wave_reduce(cm2p[k]);
      if (lane == 0) atomicAdd(&sred[k], r);
    }
    float rt = wave_reduce(tot);
    if (lane == 0) atomicAdd(&stot, rt);
  }
  __syncthreads();
  if (tid < 10) {
    float m = sred[tid] * (1.f / 512.f);
    cm2[bc * 10 + tid] = m;
    rcb[704 + c * 10 + tid] = m;
  }
  if (tid == 0) rcb[64 + c] = stot * (1.f / 5120.f);
  __syncthreads();

  if (tid < 2) sred[tid] = 0.f;
  __syncthreads();
  {
    float t0 = 0.f, t1 = 0.f;
    for (int d = tid; d < 512; d += 256) {
      t0 += b0[(size_t)bc * 512 + d];
      t1 += b1[(size_t)bc * 512 + d];
    }
    t0 = wave_reduce(t0); t1 = wave_reduce(t1);
    if (lane == 0) { atomicAdd(&sred[0], t0); atomicAdd(&sred[1], t1); }
  }
  __syncthreads();
  if (tid == 0) {
    rcb[96 + c] = sred[0] * (1.f / 512.f);
    rcb[128 + c] = sred[1] * (1.f / 512.f);
  }

  float vb2 = 0.f;
  if (tid < 10) {
    vb2 = b2[bc * 10 + tid];
    rcb[1024 + c * 10 + tid] = vb2;
  }
  if (tid < 64) {
    float s = wave_reduce(vb2);
    if (tid == 0) rcb[160 + c] = s * 0.1f;
  }
}

__global__ __launch_bounds__(256) void kw1stats(const float* __restrict__ w1,
                                                float* __restrict__ rm1,
                                                float* __restrict__ cm1,
                                                float* __restrict__ rc) {
  int idx = blockIdx.x;
  int bc = idx >> 2, hc = idx & 3;
  int b = bc >> 5, c = bc & 31;
  int tid = threadIdx.x, lane = tid & 63, wid = tid >> 6;
  __shared__ float rpart[512];
  const float* base = w1 + (size_t)bc * 262144;
  float col0 = 0.f, col1 = 0.f;
  for (int hl = 0; hl < 128; ++hl) {
    int h = hc * 128 + hl;
    float x0 = base[h * 512 + tid];
    float x1 = base[h * 512 + tid + 256];
    col0 += x0; col1 += x1;
    float r = wave_reduce(x0 + x1);
    if (lane == 0) rpart[hl * 4 + wid] = r;
  }
  __syncthreads();
  if (tid < 128) {
    float s = rpart[tid * 4] + rpart[tid * 4 + 1] + rpart[tid * 4 + 2] + rpart[tid * 4 + 3];
    cm1[(size_t)bc * 512 + hc * 128 + tid] = s * (1.f / 512.f);
  }
  atomicAdd(&rm1[(size_t)bc * 512 + tid], col0);
  atomicAdd(&rm1[(size_t)bc * 512 + tid + 256], col1);
  float bt = wave_reduce(col0 + col1);
  if (lane == 0) atomicAdd(&rc[b * 1344 + 32 + c], bt * (1.f / 262144.f));
}

__global__ void kfin(float* __restrict__ rm1) {
  int i = blockIdx.x * 256 + threadIdx.x;
  rm1[i] *= (1.f / 512.f);
}

__global__ __launch_bounds__(256) void krcgemm(
    const float* __restrict__ rc,
    const float* __restrict__ W_w0_rc, const float* __restrict__ B_w0_rc,
    const float* __restrict__ W_b0_rc, const float* __restrict__ B_b0_rc,
    const float* __restrict__ W_l1_rc, const float* __restrict__ B_l1_rc,
    const float* __restrict__ W_bias1_rc, const float* __restrict__ B_bias1_rc,
    const float* __restrict__ W_fin_rc, const float* __restrict__ B_fin_rc,
    const float* __restrict__ W_bfin_rc, const float* __restrict__ B_bfin_rc,
    float* __restrict__ t_w0, float* __restrict__ t_b0, float* __restrict__ t_l1,
    float* __restrict__ t_bias1, float* __restrict__ t_fin, float* __restrict__ u2out) {
  int blk = blockIdx.x;
  int b = blk / 312;
  int tid = threadIdx.x, lane = tid & 63, wid = tid >> 6;
  int r = (blk % 312) * 4 + wid;
  __shared__ float rcs[1344];
  for (int i = tid; i < 1344; i += 256) rcs[i] = rc[b * 1344 + i];
  __syncthreads();
  const float* W; const float* Bb; float* dst; int row;
  if (r < 512)      { W = W_w0_rc;    Bb = B_w0_rc;    row = r;       dst = t_w0 + b * 512; }
  else if (r < 544) { W = W_b0_rc;    Bb = B_b0_rc;    row = r - 512; dst = t_b0 + b * 32; }
  else if (r < 576) { W = W_l1_rc;    Bb = B_l1_rc;    row = r - 544; dst = t_l1 + b * 32; }
  else if (r < 608) { W = W_bias1_rc; Bb = B_bias1_rc; row = r - 576; dst = t_bias1 + b * 32; }
  else if (r < 928) { W = W_fin_rc;   Bb = B_fin_rc;   row = r - 608; dst = t_fin + b * 320; }
  else              { W = W_bfin_rc;  Bb = B_bfin_rc;  row = r - 928; dst = u2out + b * 320; }
  const float* wr = W + (size_t)row * 1344;
  float acc = 0.f;
  for (int j = lane; j < 1344; j += 64) acc += wr[j] * rcs[j];
  acc = wave_reduce(acc);
  if (lane == 0) dst[row] = acc + Bb[row];
}

__global__ __launch_bounds__(256) void krterm(
    const float* __restrict__ rm1, const float* __restrict__ cm0,
    const float* __restrict__ b0, const float* __restrict__ w0T,
    const float* __restrict__ W_l1_r, const float* __restrict__ B_l1_r,
    float* __restrict__ rterm) {
  int o = blockIdx.y, b = blockIdx.z;
  int w = blockIdx.x * 256 + threadIdx.x;
  const float* Wr = W_l1_r + (size_t)o * 608;
  float acc = 0.f;
#pragma unroll 4
  for (int i = 0; i < 32; ++i) acc += Wr[i] * rm1[((size_t)b * 32 + i) * 512 + w];
#pragma unroll 4
  for (int i = 0; i < 32; ++i) acc += Wr[32 + i] * cm0[((size_t)b * 32 + i) * 512 + w];
#pragma unroll 4
  for (int i = 0; i < 32; ++i) acc += Wr[64 + i] * b0[((size_t)b * 32 + i) * 512 + w];
#pragma unroll 8
  for (int i = 0; i < 512; ++i) acc += Wr[96 + i] * w0T[((size_t)b * 512 + i) * 512 + w];
  rterm[((size_t)b * 32 + o) * 512 + w] = acc + B_l1_r[o];
}

__global__ __launch_bounds__(256) void kcterm(
    const float* __restrict__ cm1, const float* __restrict__ b1,
    const float* __restrict__ rm2, const float* __restrict__ w2,
    const float* __restrict__ W_l1_c, const float* __restrict__ B_l1_c,
    const float* __restrict__ B_l1, const float* __restrict__ t_l1,
    const float* __restrict__ W_bias1, const float* __restrict__ B_bias1,
    const float* __restrict__ t_bias1,
    float* __restrict__ cterm_full, float* __restrict__ u1out) {
  int o = blockIdx.y, b = blockIdx.z;
  int h = blockIdx.x * 256 + threadIdx.x;
  const float* Wc = W_l1_c + (size_t)o * 416;
  const float* Wu = W_bias1 + (size_t)o * 416;
  float ac = 0.f, au = 0.f;
#pragma unroll 4
  for (int i = 0; i < 32; ++i) {
    float x = cm1[((size_t)b * 32 + i) * 512 + h];
    ac += Wc[i] * x; au += Wu[i] * x;
  }
#pragma unroll 4
  for (int i = 0; i < 32; ++i) {
    float x = b1[((size_t)b * 32 + i) * 512 + h];
    ac += Wc[32 + i] * x; au += Wu[32 + i] * x;
  }
#pragma unroll 4
  for (int i = 0; i < 32; ++i) {
    float x = rm2[((size_t)b * 32 + i) * 512 + h];
    ac += Wc[64 + i] * x; au += Wu[64 + i] * x;
  }
#pragma unroll 8
  for (int i = 0; i < 320; ++i) {
    float x = w2[((size_t)b * 320 + i) * 512 + h];
    ac += Wc[96 + i] * x; au += Wu[96 + i] * x;
  }
  cterm_full[((size_t)b * 32 + o) * 512 + h] = ac + B_l1_c[o] + B_l1[o] + t_l1[b * 32 + o];
  u1out[((size_t)b * 32 + o) * 512 + h] = au + B_bias1[o] + t_bias1[b * 32 + o];
}

__global__ __launch_bounds__(256) void kz0(
    const float* __restrict__ w0T, const float* __restrict__ rm1,
    const float* __restrict__ b0, const float* __restrict__ Wt_rpt,
    const float* __restrict__ B_rpt, const float* __restrict__ Wt_b0,
    const float* __restrict__ B_b0w, const float* __restrict__ t_w0,
    const float* __restrict__ t_b0, float* __restrict__ out) {
  int oc = blockIdx.y, b = blockIdx.z;
  int d = blockIdx.x * 256 + threadIdx.x;
  bool isZ = oc < 64;
  int o0 = isZ ? oc * 8 : (oc - 64) * 8;
  int stride = isZ ? 512 : 32;
  const float* W = isZ ? Wt_rpt : Wt_b0;
  float acc[8] = {0, 0, 0, 0, 0, 0, 0, 0};
  for (int i = 0; i < 512; ++i) {
    float x = w0T[((size_t)b * 512 + i) * 512 + d];
    const float* wp = W + (size_t)i * stride + o0;
#pragma unroll
    for (int oo = 0; oo < 8; ++oo) acc[oo] += wp[oo] * x;
  }
#pragma unroll 4
  for (int i = 0; i < 32; ++i) {
    float x = rm1[((size_t)b * 32 + i) * 512 + d];
    const float* wp = W + (size_t)(512 + i) * stride + o0;
#pragma unroll
    for (int oo = 0; oo < 8; ++oo) acc[oo] += wp[oo] * x;
  }
#pragma unroll 4
  for (int i = 0; i < 32; ++i) {
    float x = b0[((size_t)b * 32 + i) * 512 + d];
    const float* wp = W + (size_t)(544 + i) * stride + o0;
#pragma unroll
    for (int oo = 0; oo < 8; ++oo) acc[oo] += wp[oo] * x;
  }
  if (isZ) {
#pragma unroll
    for (int oo = 0; oo < 8; ++oo) {
      int o = o0 + oo, co = o >> 4, k = o & 15;
      out[(((size_t)b * 32 + co) * 512 + d) * 16 + k] = acc[oo] + B_rpt[o] + t_w0[b * 512 + o];
    }
  } else {
#pragma unroll
    for (int oo = 0; oo < 8; ++oo) {
      int o = o0 + oo;
      out[OUT_U0 + ((size_t)b * 32 + o) * 512 + d] = acc[oo] + B_b0w[o] + t_b0[b * 32 + o];
    }
  }
}

__global__ __launch_bounds__(256) void kzf(
    const float* __restrict__ w2, const float* __restrict__ cm1,
    const float* __restrict__ Wt_fin, const float* __restrict__ B_fin,
    const float* __restrict__ t_fin, float* __restrict__ out) {
  int oc = blockIdx.y, b = blockIdx.z;
  int d = blockIdx.x * 256 + threadIdx.x;
  int o0 = oc * 8;
  float acc[8] = {0, 0, 0, 0, 0, 0, 0, 0};
  for (int i = 0; i < 320; ++i) {
    float x = w2[((size_t)b * 320 + i) * 512 + d];
    const float* wp = Wt_fin + (size_t)i * 320 + o0;
#pragma unroll
    for (int oo = 0; oo < 8; ++oo) acc[oo] += wp[oo] * x;
  }
#pragma unroll 4
  for (int i = 0; i < 32; ++i) {
    float x = cm1[((size_t)b * 32 + i) * 512 + d];
    const float* wp = Wt_fin + (size_t)(320 + i) * 320 + o0;
#pragma unroll
    for (int oo = 0; oo < 8; ++oo) acc[oo] += wp[oo] * x;
  }
#pragma unroll
  for (int oo = 0; oo < 8; ++oo) {
    int o = o0 + oo;
    out[OUT_ZW2 + ((size_t)b * 320 + o) * 512 + d] = acc[oo] + B_fin[o] + t_fin[b * 320 + o];
  }
}

__global__ __launch_bounds__(256) void kzw1(
    const float* __restrict__ w1, const float* __restrict__ Wt_l1,
    const float* __restrict__ rterm, const float* __restrict__ cterm,
    float* __restrict__ out) {
  int h = blockIdx.x, b = blockIdx.y;
  int t = threadIdx.x;
  float2 acc[32];
#pragma unroll
  for (int o = 0; o < 32; ++o) acc[o] = make_float2(0.f, 0.f);
  const float* src = w1 + ((size_t)b * 32 * 512 + h) * 512 + 2 * t;
#pragma unroll 4
  for (int i = 0; i < 32; ++i) {
    float2 x = *(const float2*)(src + (size_t)i * 262144);
    const float* wp = Wt_l1 + i * 32;
#pragma unroll
    for (int o = 0; o < 32; ++o) {
      acc[o].x += wp[o] * x.x;
      acc[o].y += wp[o] * x.y;
    }
  }
  size_t obase = (size_t)OUT_ZW1 + ((size_t)b * 32 * 512 + h) * 512 + 2 * t;
#pragma unroll
  for (int o = 0; o < 32; ++o) {
    float cf = cterm[((size_t)b * 32 + o) * 512 + h];
    float2 rt = *(const float2*)(rterm + ((size_t)b * 32 + o) * 512 + 2 * t);
    float2 res = make_float2(acc[o].x + rt.x + cf, acc[o].y + rt.y + cf);
    *(float2*)(out + obase + (size_t)o * 262144) = res;
  }
}

extern "C" void kernel_launch(void* const* d_in, const int* in_sizes, int n_in,
                              void* d_out, int out_size, void* d_ws, size_t ws_size,
                              hipStream_t stream) {
  const float* w0 = (const float*)d_in[0];
  const float* w1 = (const float*)d_in[1];
  const float* w2 = (const float*)d_in[2];
  const float* b0 = (const float*)d_in[3];
  const float* b1 = (const float*)d_in[4];
  const float* b2 = (const float*)d_in[5];
  const float* W_w0_rpt = (const float*)d_in[6];
  const float* B_w0_rpt = (const float*)d_in[7];
  const float* W_w0_rc = (const float*)d_in[8];
  const float* B_w0_rc = (const float*)d_in[9];
  const float* W_b0 = (const float*)d_in[10];
  const float* B_b0 = (const float*)d_in[11];
  const float* W_b0_rc = (const float*)d_in[12];
  const float* B_b0_rc = (const float*)d_in[13];
  const float* W_l1 = (const float*)d_in[14];
  const float* B_l1 = (const float*)d_in[15];
  const float* W_l1_rc = (const float*)d_in[16];
  const float* B_l1_rc = (const float*)d_in[17];
  const float* W_l1_r = (const float*)d_in[18];
  const float* B_l1_r = (const float*)d_in[19];
  const float* W_l1_c = (const float*)d_in[20];
  const float* B_l1_c = (const float*)d_in[21];
  const float* W_bias1 = (const float*)d_in[22];
  const float* B_bias1 = (const float*)d_in[23];
  const float* W_bias1_rc = (const float*)d_in[24];
  const float* B_bias1_rc = (const float*)d_in[25];
  const float* W_fin_cpt = (const float*)d_in[26];
  const float* B_fin_cpt = (const float*)d_in[27];
  const float* W_fin_rc = (const float*)d_in[28];
  const float* B_fin_rc = (const float*)d_in[29];
  const float* W_bfin_rc = (const float*)d_in[30];
  const float* B_bfin_rc = (const float*)d_in[31];
  float* ws = (float*)d_ws;
  float* out = (float*)d_out;

  // custom zero of atomic targets only (rm1 + rc = 141824 floats):
  // rocclr fillBufferAligned ran at 13 GB/s (164 us) for this — do it ourselves.
  kzero<<<dim3((131072 + 10752 + 255) / 256), 256, 0, stream>>>(ws);

  ktrans<<<dim3((512 * 576 + 255) / 256), 256, 0, stream>>>(W_w0_rpt, ws + WS_WT_RPT, 512, 576);
  ktrans<<<dim3((32 * 576 + 255) / 256), 256, 0, stream>>>(W_b0, ws + WS_WT_B0, 32, 576);
  ktrans<<<dim3((320 * 352 + 255) / 256), 256, 0, stream>>>(W_fin_cpt, ws + WS_WT_FIN, 320, 352);
  ktrans<<<dim3((32 * 32 + 255) / 256), 256, 0, stream>>>(W_l1, ws + WS_WT_L1, 32, 32);
  ktransw0<<<dim3(256), 256, 0, stream>>>(w0, ws + WS_W0T);

  kstats<<<dim3(256), 256, 0, stream>>>(w0, w2, b0, b1, b2, ws + WS_CM0, ws + WS_RM2,
                                        ws + WS_CM2, ws + WS_RC);
  kw1stats<<<dim3(1024), 256, 0, stream>>>(w1, ws + WS_RM1, ws + WS_CM1, ws + WS_RC);
  kfin<<<dim3(512), 256, 0, stream>>>(ws + WS_RM1);

  krcgemm<<<dim3(8 * 312), 256, 0, stream>>>(
      ws + WS_RC, W_w0_rc, B_w0_rc, W_b0_rc, B_b0_rc, W_l1_rc, B_l1_rc, W_bias1_rc,
      B_bias1_rc, W_fin_rc, B_fin_rc, W_bfin_rc, B_bfin_rc, ws + WS_TW0, ws + WS_TB0,
      ws + WS_TL1, ws + WS_TBIAS1, ws + WS_TFIN, out + OUT_U2);

  krterm<<<dim3(2, 32, 8), 256, 0, stream>>>(ws + WS_RM1, ws + WS_CM0, b0, ws + WS_W0T,
                                             W_l1_r, B_l1_r, ws + WS_RTERM);
  kcterm<<<dim3(2, 32, 8), 256, 0, stream>>>(ws + WS_CM1, b1, ws + WS_RM2, w2, W_l1_c,
                                             B_l1_c, B_l1, ws + WS_TL1, W_bias1, B_bias1,
                                             ws + WS_TBIAS1, ws + WS_CTERM, out + OUT_U1);
  kz0<<<dim3(2, 68, 8), 256, 0, stream>>>(ws + WS_W0T, ws + WS_RM1, b0, ws + WS_WT_RPT,
                                          B_w0_rpt, ws + WS_WT_B0, B_b0, ws + WS_TW0,
                                          ws + WS_TB0, out);
  kzf<<<dim3(2, 40, 8), 256, 0, stream>>>(w2, ws + WS_CM1, ws + WS_WT_FIN, B_fin_cpt,
                                          ws + WS_TFIN, out);
  kzw1<<<dim3(512, 8), 256, 0, stream>>>(w1, ws + WS_WT_L1, ws + WS_RTERM, ws + WS_CTERM,
                                         out);
  (void)in_sizes; (void)n_in; (void)out_size; (void)ws_size;
}

// Round 3
// 473.603 us; speedup vs baseline: 1.0787x; 1.0787x over previous
//
#include <hip/hip_runtime.h>

// ---------------- constants ----------------
// B=8, C=32, CO=32, NIN=16, NOUT=10, D1=D2=512, NRC=1344
// outputs (fp32, concatenated): zw0[8,32,512,16] zw1[8,32,512,512] zw2[8,32,10,512]
//                               u0[8,32,512] u1[8,32,512] u2[8,32,10]
#define OUT_ZW1 2097152u
#define OUT_ZW2 69206016u
#define OUT_U0  70516736u
#define OUT_U1  70647808u
#define OUT_U2  70778880u

// workspace layout (floats) — ~13.3 MB total
#define WS_RM1      0u        // raw col-sums of w1 (normalize by 1/512 at use)
#define WS_CM1      131072u
#define WS_CM0      262144u
#define WS_RM2      393216u
#define WS_CM2      524288u
#define WS_RC       526848u
#define WS_TW0      537600u
#define WS_TB0      541696u
#define WS_TL1      541952u
#define WS_TBIAS1   542208u
#define WS_TFIN     542464u
#define WS_RTERM    545024u
#define WS_CTERM    676096u
#define WS_W0T      807168u
#define WS_WT_RPT   2904320u
#define WS_WT_B0    3199232u
#define WS_WT_FIN   3217664u
#define WS_WT_L1    3330304u

static __device__ __forceinline__ float wave_reduce(float v) {
#pragma unroll
  for (int off = 32; off > 0; off >>= 1) v += __shfl_down(v, off);
  return v;
}

// ---- fused setup: zero atomic targets + all weight transposes + w0 transpose ----
// block ranges: [0,554) zero | [554,1706) W_w0_rpt^T | [1706,1778) W_b0^T |
//               [1778,2218) W_fin_cpt^T | [2218,2222) W_l1^T | [2222,2478) w0T
__global__ __launch_bounds__(256) void kprep(
    const float* __restrict__ w0, const float* __restrict__ W_w0_rpt,
    const float* __restrict__ W_b0, const float* __restrict__ W_fin_cpt,
    const float* __restrict__ W_l1, float* __restrict__ ws) {
  int blk = blockIdx.x, tid = threadIdx.x;
  if (blk < 554) {
    int i = blk * 256 + tid;  // 141824 = 554*256 exactly
    if (i < 131072) ws[WS_RM1 + i] = 0.f;
    else ws[WS_RC + (i - 131072)] = 0.f;
  } else if (blk < 1706) {
    int idx = (blk - 554) * 256 + tid;          // 294912: (512,576)
    int r = idx / 576, c = idx - r * 576;
    ws[WS_WT_RPT + c * 512 + r] = W_w0_rpt[idx];
  } else if (blk < 1778) {
    int idx = (blk - 1706) * 256 + tid;         // 18432: (32,576)
    int r = idx / 576, c = idx - r * 576;
    ws[WS_WT_B0 + c * 32 + r] = W_b0[idx];
  } else if (blk < 2218) {
    int idx = (blk - 1778) * 256 + tid;         // 112640: (320,352)
    int r = idx / 352, c = idx - r * 352;
    ws[WS_WT_FIN + c * 320 + r] = W_fin_cpt[idx];
  } else if (blk < 2222) {
    int idx = (blk - 2218) * 256 + tid;         // 1024: (32,32)
    int r = idx >> 5, c = idx & 31;
    ws[WS_WT_L1 + c * 32 + r] = W_l1[idx];
  } else {
    int bc = blk - 2222;                        // 256 blocks: w0 -> w0T
    int b = bc >> 5, c = bc & 31;
    for (int k = 0; k < 16; ++k)
      for (int d = tid; d < 512; d += 256)
        ws[WS_W0T + ((size_t)(b * 512 + c * 16 + k)) * 512 + d] =
            w0[((size_t)bc * 512 + d) * 16 + k];
  }
}

__global__ __launch_bounds__(256) void kstats(
    const float* __restrict__ w0, const float* __restrict__ w2,
    const float* __restrict__ b0, const float* __restrict__ b1,
    const float* __restrict__ b2, float* __restrict__ cm0, float* __restrict__ rm2,
    float* __restrict__ cm2, float* __restrict__ rc) {
  int bc = blockIdx.x;
  int b = bc >> 5, c = bc & 31;
  int tid = threadIdx.x, lane = tid & 63;
  __shared__ float sred[16];
  __shared__ float stot;
  float* rcb = rc + b * 1344;

  if (tid < 16) sred[tid] = 0.f;
  if (tid == 0) stot = 0.f;
  __syncthreads();
  {
    float rm0p[16];
#pragma unroll
    for (int k = 0; k < 16; ++k) rm0p[k] = 0.f;
    float tot = 0.f;
    for (int d = tid; d < 512; d += 256) {
      const float4* p = (const float4*)(w0 + ((size_t)bc * 512 + d) * 16);
      float s = 0.f;
#pragma unroll
      for (int q = 0; q < 4; ++q) {
        float4 v = p[q];
        s += v.x + v.y + v.z + v.w;
        rm0p[q * 4 + 0] += v.x; rm0p[q * 4 + 1] += v.y;
        rm0p[q * 4 + 2] += v.z; rm0p[q * 4 + 3] += v.w;
      }
      cm0[(size_t)bc * 512 + d] = s * (1.f / 16.f);
      tot += s;
    }
#pragma unroll
    for (int k = 0; k < 16; ++k) {
      float r = wave_reduce(rm0p[k]);
      if (lane == 0) atomicAdd(&sred[k], r);
    }
    float rt = wave_reduce(tot);
    if (lane == 0) atomicAdd(&stot, rt);
  }
  __syncthreads();
  if (tid < 16) rcb[192 + c * 16 + tid] = sred[tid] * (1.f / 512.f);
  if (tid == 0) rcb[c] = stot * (1.f / 8192.f);
  __syncthreads();

  if (tid < 10) sred[tid] = 0.f;
  if (tid == 0) stot = 0.f;
  __syncthreads();
  {
    float cm2p[10];
#pragma unroll
    for (int k = 0; k < 10; ++k) cm2p[k] = 0.f;
    float tot = 0.f;
    for (int d = tid; d < 512; d += 256) {
      float s = 0.f;
#pragma unroll
      for (int k = 0; k < 10; ++k) {
        float v = w2[((size_t)bc * 10 + k) * 512 + d];
        s += v; cm2p[k] += v;
      }
      rm2[(size_t)bc * 512 + d] = s * 0.1f;
      tot += s;
    }
#pragma unroll
    for (int k = 0; k < 10; ++k) {
      float r = wave_reduce(cm2p[k]);
      if (lane == 0) atomicAdd(&sred[k], r);
    }
    float rt = wave_reduce(tot);
    if (lane == 0) atomicAdd(&stot, rt);
  }
  __syncthreads();
  if (tid < 10) {
    float m = sred[tid] * (1.f / 512.f);
    cm2[bc * 10 + tid] = m;
    rcb[704 + c * 10 + tid] = m;
  }
  if (tid == 0) rcb[64 + c] = stot * (1.f / 5120.f);
  __syncthreads();

  if (tid < 2) sred[tid] = 0.f;
  __syncthreads();
  {
    float t0 = 0.f, t1 = 0.f;
    for (int d = tid; d < 512; d += 256) {
      t0 += b0[(size_t)bc * 512 + d];
      t1 += b1[(size_t)bc * 512 + d];
    }
    t0 = wave_reduce(t0); t1 = wave_reduce(t1);
    if (lane == 0) { atomicAdd(&sred[0], t0); atomicAdd(&sred[1], t1); }
  }
  __syncthreads();
  if (tid == 0) {
    rcb[96 + c] = sred[0] * (1.f / 512.f);
    rcb[128 + c] = sred[1] * (1.f / 512.f);
  }

  float vb2 = 0.f;
  if (tid < 10) {
    vb2 = b2[bc * 10 + tid];
    rcb[1024 + c * 10 + tid] = vb2;
  }
  if (tid < 64) {
    float s = wave_reduce(vb2);
    if (tid == 0) rcb[160 + c] = s * 0.1f;
  }
}

__global__ __launch_bounds__(256) void kw1stats(const float* __restrict__ w1,
                                                float* __restrict__ rm1,
                                                float* __restrict__ cm1,
                                                float* __restrict__ rc) {
  int idx = blockIdx.x;
  int bc = idx >> 2, hc = idx & 3;
  int b = bc >> 5, c = bc & 31;
  int tid = threadIdx.x, lane = tid & 63, wid = tid >> 6;
  __shared__ float rpart[512];
  const float* base = w1 + (size_t)bc * 262144 + (size_t)hc * 128 * 512;
  float col0 = 0.f, col1 = 0.f;
  for (int hl = 0; hl < 128; ++hl) {
    float2 x = *(const float2*)(base + hl * 512 + 2 * tid);
    col0 += x.x; col1 += x.y;
    float r = wave_reduce(x.x + x.y);
    if (lane == 0) rpart[hl * 4 + wid] = r;
  }
  __syncthreads();
  if (tid < 128) {
    float s = rpart[tid * 4] + rpart[tid * 4 + 1] + rpart[tid * 4 + 2] + rpart[tid * 4 + 3];
    cm1[(size_t)bc * 512 + hc * 128 + tid] = s * (1.f / 512.f);
  }
  atomicAdd(&rm1[(size_t)bc * 512 + 2 * tid], col0);
  atomicAdd(&rm1[(size_t)bc * 512 + 2 * tid + 1], col1);
  float bt = wave_reduce(col0 + col1);
  if (lane == 0) atomicAdd(&rc[b * 1344 + 32 + c], bt * (1.f / 262144.f));
}

__global__ __launch_bounds__(256) void krcgemm(
    const float* __restrict__ rc,
    const float* __restrict__ W_w0_rc, const float* __restrict__ B_w0_rc,
    const float* __restrict__ W_b0_rc, const float* __restrict__ B_b0_rc,
    const float* __restrict__ W_l1_rc, const float* __restrict__ B_l1_rc,
    const float* __restrict__ W_bias1_rc, const float* __restrict__ B_bias1_rc,
    const float* __restrict__ W_fin_rc, const float* __restrict__ B_fin_rc,
    const float* __restrict__ W_bfin_rc, const float* __restrict__ B_bfin_rc,
    float* __restrict__ t_w0, float* __restrict__ t_b0, float* __restrict__ t_l1,
    float* __restrict__ t_bias1, float* __restrict__ t_fin, float* __restrict__ u2out) {
  int blk = blockIdx.x;
  int b = blk / 312;
  int tid = threadIdx.x, lane = tid & 63, wid = tid >> 6;
  int r = (blk % 312) * 4 + wid;
  __shared__ float rcs[1344];
  for (int i = tid; i < 1344; i += 256) rcs[i] = rc[b * 1344 + i];
  __syncthreads();
  const float* W; const float* Bb; float* dst; int row;
  if (r < 512)      { W = W_w0_rc;    Bb = B_w0_rc;    row = r;       dst = t_w0 + b * 512; }
  else if (r < 544) { W = W_b0_rc;    Bb = B_b0_rc;    row = r - 512; dst = t_b0 + b * 32; }
  else if (r < 576) { W = W_l1_rc;    Bb = B_l1_rc;    row = r - 544; dst = t_l1 + b * 32; }
  else if (r < 608) { W = W_bias1_rc; Bb = B_bias1_rc; row = r - 576; dst = t_bias1 + b * 32; }
  else if (r < 928) { W = W_fin_rc;   Bb = B_fin_rc;   row = r - 608; dst = t_fin + b * 320; }
  else              { W = W_bfin_rc;  Bb = B_bfin_rc;  row = r - 928; dst = u2out + b * 320; }
  const float* wr = W + (size_t)row * 1344;
  float acc = 0.f;
  for (int j = lane; j < 1344; j += 64) acc += wr[j] * rcs[j];
  acc = wave_reduce(acc);
  if (lane == 0) dst[row] = acc + Bb[row];
}

// ---- fused rterm (oy<32) / cterm+u1 (oy>=32) ----
__global__ __launch_bounds__(256) void krcterm(
    const float* __restrict__ rm1, const float* __restrict__ cm0,
    const float* __restrict__ b0, const float* __restrict__ w0T,
    const float* __restrict__ W_l1_r, const float* __restrict__ B_l1_r,
    float* __restrict__ rterm,
    const float* __restrict__ cm1, const float* __restrict__ b1,
    const float* __restrict__ rm2, const float* __restrict__ w2,
    const float* __restrict__ W_l1_c, const float* __restrict__ B_l1_c,
    const float* __restrict__ B_l1, const float* __restrict__ t_l1,
    const float* __restrict__ W_bias1, const float* __restrict__ B_bias1,
    const float* __restrict__ t_bias1,
    float* __restrict__ cterm_full, float* __restrict__ u1out) {
  int oy = blockIdx.y, b = blockIdx.z;
  int p = blockIdx.x * 256 + threadIdx.x;
  if (oy < 32) {
    int o = oy;
    const float* Wr = W_l1_r + (size_t)o * 608;
    float acc = 0.f;
#pragma unroll 4
    for (int i = 0; i < 32; ++i)
      acc += Wr[i] * (rm1[((size_t)b * 32 + i) * 512 + p] * (1.f / 512.f));
#pragma unroll 4
    for (int i = 0; i < 32; ++i) acc += Wr[32 + i] * cm0[((size_t)b * 32 + i) * 512 + p];
#pragma unroll 4
    for (int i = 0; i < 32; ++i) acc += Wr[64 + i] * b0[((size_t)b * 32 + i) * 512 + p];
#pragma unroll 8
    for (int i = 0; i < 512; ++i) acc += Wr[96 + i] * w0T[((size_t)b * 512 + i) * 512 + p];
    rterm[((size_t)b * 32 + o) * 512 + p] = acc + B_l1_r[o];
  } else {
    int o = oy - 32;
    const float* Wc = W_l1_c + (size_t)o * 416;
    const float* Wu = W_bias1 + (size_t)o * 416;
    float ac = 0.f, au = 0.f;
#pragma unroll 4
    for (int i = 0; i < 32; ++i) {
      float x = cm1[((size_t)b * 32 + i) * 512 + p];
      ac += Wc[i] * x; au += Wu[i] * x;
    }
#pragma unroll 4
    for (int i = 0; i < 32; ++i) {
      float x = b1[((size_t)b * 32 + i) * 512 + p];
      ac += Wc[32 + i] * x; au += Wu[32 + i] * x;
    }
#pragma unroll 4
    for (int i = 0; i < 32; ++i) {
      float x = rm2[((size_t)b * 32 + i) * 512 + p];
      ac += Wc[64 + i] * x; au += Wu[64 + i] * x;
    }
#pragma unroll 8
    for (int i = 0; i < 320; ++i) {
      float x = w2[((size_t)b * 320 + i) * 512 + p];
      ac += Wc[96 + i] * x; au += Wu[96 + i] * x;
    }
    cterm_full[((size_t)b * 32 + o) * 512 + p] = ac + B_l1_c[o] + B_l1[o] + t_l1[b * 32 + o];
    u1out[((size_t)b * 32 + o) * 512 + p] = au + B_bias1[o] + t_bias1[b * 32 + o];
  }
}

__global__ __launch_bounds__(256) void kz0(
    const float* __restrict__ w0T, const float* __restrict__ rm1,
    const float* __restrict__ b0, const float* __restrict__ Wt_rpt,
    const float* __restrict__ B_rpt, const float* __restrict__ Wt_b0,
    const float* __restrict__ B_b0w, const float* __restrict__ t_w0,
    const float* __restrict__ t_b0, float* __restrict__ out) {
  int oc = blockIdx.y, b = blockIdx.z;
  int d = blockIdx.x * 256 + threadIdx.x;
  bool isZ = oc < 64;
  int o0 = isZ ? oc * 8 : (oc - 64) * 8;
  int stride = isZ ? 512 : 32;
  const float* W = isZ ? Wt_rpt : Wt_b0;
  float acc[8] = {0, 0, 0, 0, 0, 0, 0, 0};
  for (int i = 0; i < 512; ++i) {
    float x = w0T[((size_t)b * 512 + i) * 512 + d];
    const float* wp = W + (size_t)i * stride + o0;
#pragma unroll
    for (int oo = 0; oo < 8; ++oo) acc[oo] += wp[oo] * x;
  }
#pragma unroll 4
  for (int i = 0; i < 32; ++i) {
    float x = rm1[((size_t)b * 32 + i) * 512 + d] * (1.f / 512.f);
    const float* wp = W + (size_t)(512 + i) * stride + o0;
#pragma unroll
    for (int oo = 0; oo < 8; ++oo) acc[oo] += wp[oo] * x;
  }
#pragma unroll 4
  for (int i = 0; i < 32; ++i) {
    float x = b0[((size_t)b * 32 + i) * 512 + d];
    const float* wp = W + (size_t)(544 + i) * stride + o0;
#pragma unroll
    for (int oo = 0; oo < 8; ++oo) acc[oo] += wp[oo] * x;
  }
  if (isZ) {
#pragma unroll
    for (int oo = 0; oo < 8; ++oo) {
      int o = o0 + oo, co = o >> 4, k = o & 15;
      out[(((size_t)b * 32 + co) * 512 + d) * 16 + k] = acc[oo] + B_rpt[o] + t_w0[b * 512 + o];
    }
  } else {
#pragma unroll
    for (int oo = 0; oo < 8; ++oo) {
      int o = o0 + oo;
      out[OUT_U0 + ((size_t)b * 32 + o) * 512 + d] = acc[oo] + B_b0w[o] + t_b0[b * 32 + o];
    }
  }
}

__global__ __launch_bounds__(256) void kzf(
    const float* __restrict__ w2, const float* __restrict__ cm1,
    const float* __restrict__ Wt_fin, const float* __restrict__ B_fin,
    const float* __restrict__ t_fin, float* __restrict__ out) {
  int oc = blockIdx.y, b = blockIdx.z;
  int d = blockIdx.x * 256 + threadIdx.x;
  int o0 = oc * 8;
  float acc[8] = {0, 0, 0, 0, 0, 0, 0, 0};
  for (int i = 0; i < 320; ++i) {
    float x = w2[((size_t)b * 320 + i) * 512 + d];
    const float* wp = Wt_fin + (size_t)i * 320 + o0;
#pragma unroll
    for (int oo = 0; oo < 8; ++oo) acc[oo] += wp[oo] * x;
  }
#pragma unroll 4
  for (int i = 0; i < 32; ++i) {
    float x = cm1[((size_t)b * 32 + i) * 512 + d];
    const float* wp = Wt_fin + (size_t)(320 + i) * 320 + o0;
#pragma unroll
    for (int oo = 0; oo < 8; ++oo) acc[oo] += wp[oo] * x;
  }
#pragma unroll
  for (int oo = 0; oo < 8; ++oo) {
    int o = o0 + oo;
    out[OUT_ZW2 + ((size_t)b * 320 + o) * 512 + d] = acc[oo] + B_fin[o] + t_fin[b * 320 + o];
  }
}

// ---- zw1: float4, 2 rows per block. grid (256, 8) ----
__global__ __launch_bounds__(256) void kzw1(
    const float* __restrict__ w1, const float* __restrict__ Wt_l1,
    const float* __restrict__ rterm, const float* __restrict__ cterm,
    float* __restrict__ out) {
  int hp = blockIdx.x, b = blockIdx.y;
  int t = threadIdx.x;
  int h0 = hp * 2;
  int hoff = t >> 7;           // 0 or 1
  int w = (t & 127) * 4;       // 0..508
  float4 acc[32];
#pragma unroll
  for (int o = 0; o < 32; ++o) acc[o] = make_float4(0.f, 0.f, 0.f, 0.f);
  const float* src = w1 + ((size_t)b * 32 * 512 + h0) * 512 + 4 * t;  // 4t = hoff*512 + w
#pragma unroll 4
  for (int i = 0; i < 32; ++i) {
    float4 x = *(const float4*)(src + (size_t)i * 262144);
    const float* wp = Wt_l1 + i * 32;
#pragma unroll
    for (int o = 0; o < 32; ++o) {
      acc[o].x += wp[o] * x.x;
      acc[o].y += wp[o] * x.y;
      acc[o].z += wp[o] * x.z;
      acc[o].w += wp[o] * x.w;
    }
  }
  int h = h0 + hoff;
#pragma unroll
  for (int o = 0; o < 32; ++o) {
    float cf = cterm[((size_t)b * 32 + o) * 512 + h];
    float4 rt = *(const float4*)(rterm + ((size_t)b * 32 + o) * 512 + w);
    float4 res = make_float4(acc[o].x + rt.x + cf, acc[o].y + rt.y + cf,
                             acc[o].z + rt.z + cf, acc[o].w + rt.w + cf);
    *(float4*)(out + (size_t)OUT_ZW1 + (((size_t)b * 32 + o) * 512 + h) * 512 + w) = res;
  }
}

extern "C" void kernel_launch(void* const* d_in, const int* in_sizes, int n_in,
                              void* d_out, int out_size, void* d_ws, size_t ws_size,
                              hipStream_t stream) {
  const float* w0 = (const float*)d_in[0];
  const float* w1 = (const float*)d_in[1];
  const float* w2 = (const float*)d_in[2];
  const float* b0 = (const float*)d_in[3];
  const float* b1 = (const float*)d_in[4];
  const float* b2 = (const float*)d_in[5];
  const float* W_w0_rpt = (const float*)d_in[6];
  const float* B_w0_rpt = (const float*)d_in[7];
  const float* W_w0_rc = (const float*)d_in[8];
  const float* B_w0_rc = (const float*)d_in[9];
  const float* W_b0 = (const float*)d_in[10];
  const float* B_b0 = (const float*)d_in[11];
  const float* W_b0_rc = (const float*)d_in[12];
  const float* B_b0_rc = (const float*)d_in[13];
  const float* W_l1 = (const float*)d_in[14];
  const float* B_l1 = (const float*)d_in[15];
  const float* W_l1_rc = (const float*)d_in[16];
  const float* B_l1_rc = (const float*)d_in[17];
  const float* W_l1_r = (const float*)d_in[18];
  const float* B_l1_r = (const float*)d_in[19];
  const float* W_l1_c = (const float*)d_in[20];
  const float* B_l1_c = (const float*)d_in[21];
  const float* W_bias1 = (const float*)d_in[22];
  const float* B_bias1 = (const float*)d_in[23];
  const float* W_bias1_rc = (const float*)d_in[24];
  const float* B_bias1_rc = (const float*)d_in[25];
  const float* W_fin_cpt = (const float*)d_in[26];
  const float* B_fin_cpt = (const float*)d_in[27];
  const float* W_fin_rc = (const float*)d_in[28];
  const float* B_fin_rc = (const float*)d_in[29];
  const float* W_bfin_rc = (const float*)d_in[30];
  const float* B_bfin_rc = (const float*)d_in[31];
  float* ws = (float*)d_ws;
  float* out = (float*)d_out;

  kprep<<<dim3(2478), 256, 0, stream>>>(w0, W_w0_rpt, W_b0, W_fin_cpt, W_l1, ws);

  kstats<<<dim3(256), 256, 0, stream>>>(w0, w2, b0, b1, b2, ws + WS_CM0, ws + WS_RM2,
                                        ws + WS_CM2, ws + WS_RC);
  kw1stats<<<dim3(1024), 256, 0, stream>>>(w1, ws + WS_RM1, ws + WS_CM1, ws + WS_RC);

  krcgemm<<<dim3(8 * 312), 256, 0, stream>>>(
      ws + WS_RC, W_w0_rc, B_w0_rc, W_b0_rc, B_b0_rc, W_l1_rc, B_l1_rc, W_bias1_rc,
      B_bias1_rc, W_fin_rc, B_fin_rc, W_bfin_rc, B_bfin_rc, ws + WS_TW0, ws + WS_TB0,
      ws + WS_TL1, ws + WS_TBIAS1, ws + WS_TFIN, out + OUT_U2);

  krcterm<<<dim3(2, 64, 8), 256, 0, stream>>>(
      ws + WS_RM1, ws + WS_CM0, b0, ws + WS_W0T, W_l1_r, B_l1_r, ws + WS_RTERM,
      ws + WS_CM1, b1, ws + WS_RM2, w2, W_l1_c, B_l1_c, B_l1, ws + WS_TL1, W_bias1,
      B_bias1, ws + WS_TBIAS1, ws + WS_CTERM, out + OUT_U1);

  kz0<<<dim3(2, 68, 8), 256, 0, stream>>>(ws + WS_W0T, ws + WS_RM1, b0, ws + WS_WT_RPT,
                                          B_w0_rpt, ws + WS_WT_B0, B_b0, ws + WS_TW0,
                                          ws + WS_TB0, out);
  kzf<<<dim3(2, 40, 8), 256, 0, stream>>>(w2, ws + WS_CM1, ws + WS_WT_FIN, B_fin_cpt,
                                          ws + WS_TFIN, out);
  kzw1<<<dim3(256, 8), 256, 0, stream>>>(w1, ws + WS_WT_L1, ws + WS_RTERM, ws + WS_CTERM,
                                         out);
  (void)in_sizes; (void)n_in; (void)out_size; (void)ws_size;
}

// Round 4
// 422.075 us; speedup vs baseline: 1.2104x; 1.1221x over previous
//
#include <hip/hip_runtime.h>

// ---------------- constants ----------------
// B=8, C=32, CO=32, NIN=16, NOUT=10, D1=D2=512, NRC=1344
// outputs (fp32, concatenated): zw0[8,32,512,16] zw1[8,32,512,512] zw2[8,32,10,512]
//                               u0[8,32,512] u1[8,32,512] u2[8,32,10]
#define OUT_ZW1 2097152u
#define OUT_ZW2 69206016u
#define OUT_U0  70516736u
#define OUT_U1  70647808u
#define OUT_U2  70778880u

// workspace layout (floats)
#define WS_RM1      0u        // raw col-sums of w1 (normalize by 1/512 at use)
#define WS_CM1      131072u
#define WS_CM0      262144u
#define WS_RM2      393216u
#define WS_CM2      524288u
#define WS_RC       526848u
#define WS_TW0      537600u
#define WS_TB0      541696u
#define WS_TL1      541952u
#define WS_TBIAS1   542208u
#define WS_TFIN     542464u
#define WS_RTERM    545024u
#define WS_CTERM    676096u
#define WS_W0T      807168u
#define WS_WT_L1    3330304u

static __device__ __forceinline__ float wave_reduce(float v) {
#pragma unroll
  for (int off = 32; off > 0; off >>= 1) v += __shfl_down(v, off);
  return v;
}

// ---- fused setup: zero atomic targets + W_l1 transpose + w0 transpose ----
// block ranges: [0,554) zero | [554,558) W_l1^T | [558,814) w0T
__global__ __launch_bounds__(256) void kprep(
    const float* __restrict__ w0, const float* __restrict__ W_l1,
    float* __restrict__ ws) {
  int blk = blockIdx.x, tid = threadIdx.x;
  if (blk < 554) {
    int i = blk * 256 + tid;  // 141824 = 554*256 exactly
    if (i < 131072) ws[WS_RM1 + i] = 0.f;
    else ws[WS_RC + (i - 131072)] = 0.f;
  } else if (blk < 558) {
    int idx = (blk - 554) * 256 + tid;          // 1024: (32,32)
    int r = idx >> 5, c = idx & 31;
    ws[WS_WT_L1 + c * 32 + r] = W_l1[idx];
  } else {
    int bc = blk - 558;                         // 256 blocks: w0 -> w0T
    int b = bc >> 5, c = bc & 31;
    for (int k = 0; k < 16; ++k)
      for (int d = tid; d < 512; d += 256)
        ws[WS_W0T + ((size_t)(b * 512 + c * 16 + k)) * 512 + d] =
            w0[((size_t)bc * 512 + d) * 16 + k];
  }
}

__global__ __launch_bounds__(256) void kstats(
    const float* __restrict__ w0, const float* __restrict__ w2,
    const float* __restrict__ b0, const float* __restrict__ b1,
    const float* __restrict__ b2, float* __restrict__ cm0, float* __restrict__ rm2,
    float* __restrict__ cm2, float* __restrict__ rc) {
  int bc = blockIdx.x;
  int b = bc >> 5, c = bc & 31;
  int tid = threadIdx.x, lane = tid & 63;
  __shared__ float sred[16];
  __shared__ float stot;
  float* rcb = rc + b * 1344;

  if (tid < 16) sred[tid] = 0.f;
  if (tid == 0) stot = 0.f;
  __syncthreads();
  {
    float rm0p[16];
#pragma unroll
    for (int k = 0; k < 16; ++k) rm0p[k] = 0.f;
    float tot = 0.f;
    for (int d = tid; d < 512; d += 256) {
      const float4* p = (const float4*)(w0 + ((size_t)bc * 512 + d) * 16);
      float s = 0.f;
#pragma unroll
      for (int q = 0; q < 4; ++q) {
        float4 v = p[q];
        s += v.x + v.y + v.z + v.w;
        rm0p[q * 4 + 0] += v.x; rm0p[q * 4 + 1] += v.y;
        rm0p[q * 4 + 2] += v.z; rm0p[q * 4 + 3] += v.w;
      }
      cm0[(size_t)bc * 512 + d] = s * (1.f / 16.f);
      tot += s;
    }
#pragma unroll
    for (int k = 0; k < 16; ++k) {
      float r = wave_reduce(rm0p[k]);
      if (lane == 0) atomicAdd(&sred[k], r);
    }
    float rt = wave_reduce(tot);
    if (lane == 0) atomicAdd(&stot, rt);
  }
  __syncthreads();
  if (tid < 16) rcb[192 + c * 16 + tid] = sred[tid] * (1.f / 512.f);
  if (tid == 0) rcb[c] = stot * (1.f / 8192.f);
  __syncthreads();

  if (tid < 10) sred[tid] = 0.f;
  if (tid == 0) stot = 0.f;
  __syncthreads();
  {
    float cm2p[10];
#pragma unroll
    for (int k = 0; k < 10; ++k) cm2p[k] = 0.f;
    float tot = 0.f;
    for (int d = tid; d < 512; d += 256) {
      float s = 0.f;
#pragma unroll
      for (int k = 0; k < 10; ++k) {
        float v = w2[((size_t)bc * 10 + k) * 512 + d];
        s += v; cm2p[k] += v;
      }
      rm2[(size_t)bc * 512 + d] = s * 0.1f;
      tot += s;
    }
#pragma unroll
    for (int k = 0; k < 10; ++k) {
      float r = wave_reduce(cm2p[k]);
      if (lane == 0) atomicAdd(&sred[k], r);
    }
    float rt = wave_reduce(tot);
    if (lane == 0) atomicAdd(&stot, rt);
  }
  __syncthreads();
  if (tid < 10) {
    float m = sred[tid] * (1.f / 512.f);
    cm2[bc * 10 + tid] = m;
    rcb[704 + c * 10 + tid] = m;
  }
  if (tid == 0) rcb[64 + c] = stot * (1.f / 5120.f);
  __syncthreads();

  if (tid < 2) sred[tid] = 0.f;
  __syncthreads();
  {
    float t0 = 0.f, t1 = 0.f;
    for (int d = tid; d < 512; d += 256) {
      t0 += b0[(size_t)bc * 512 + d];
      t1 += b1[(size_t)bc * 512 + d];
    }
    t0 = wave_reduce(t0); t1 = wave_reduce(t1);
    if (lane == 0) { atomicAdd(&sred[0], t0); atomicAdd(&sred[1], t1); }
  }
  __syncthreads();
  if (tid == 0) {
    rcb[96 + c] = sred[0] * (1.f / 512.f);
    rcb[128 + c] = sred[1] * (1.f / 512.f);
  }

  float vb2 = 0.f;
  if (tid < 10) {
    vb2 = b2[bc * 10 + tid];
    rcb[1024 + c * 10 + tid] = vb2;
  }
  if (tid < 64) {
    float s = wave_reduce(vb2);
    if (tid == 0) rcb[160 + c] = s * 0.1f;
  }
}

__global__ __launch_bounds__(256) void kw1stats(const float* __restrict__ w1,
                                                float* __restrict__ rm1,
                                                float* __restrict__ cm1,
                                                float* __restrict__ rc) {
  int idx = blockIdx.x;
  int bc = idx >> 2, hc = idx & 3;
  int b = bc >> 5, c = bc & 31;
  int tid = threadIdx.x, lane = tid & 63, wid = tid >> 6;
  __shared__ float rpart[512];
  const float* base = w1 + (size_t)bc * 262144 + (size_t)hc * 128 * 512;
  float col0 = 0.f, col1 = 0.f;
  for (int hl = 0; hl < 128; ++hl) {
    float2 x = *(const float2*)(base + hl * 512 + 2 * tid);
    col0 += x.x; col1 += x.y;
    float r = wave_reduce(x.x + x.y);
    if (lane == 0) rpart[hl * 4 + wid] = r;
  }
  __syncthreads();
  if (tid < 128) {
    float s = rpart[tid * 4] + rpart[tid * 4 + 1] + rpart[tid * 4 + 2] + rpart[tid * 4 + 3];
    cm1[(size_t)bc * 512 + hc * 128 + tid] = s * (1.f / 512.f);
  }
  atomicAdd(&rm1[(size_t)bc * 512 + 2 * tid], col0);
  atomicAdd(&rm1[(size_t)bc * 512 + 2 * tid + 1], col1);
  float bt = wave_reduce(col0 + col1);
  if (lane == 0) atomicAdd(&rc[b * 1344 + 32 + c], bt * (1.f / 262144.f));
}

__global__ __launch_bounds__(256) void krcgemm(
    const float* __restrict__ rc,
    const float* __restrict__ W_w0_rc, const float* __restrict__ B_w0_rc,
    const float* __restrict__ W_b0_rc, const float* __restrict__ B_b0_rc,
    const float* __restrict__ W_l1_rc, const float* __restrict__ B_l1_rc,
    const float* __restrict__ W_bias1_rc, const float* __restrict__ B_bias1_rc,
    const float* __restrict__ W_fin_rc, const float* __restrict__ B_fin_rc,
    const float* __restrict__ W_bfin_rc, const float* __restrict__ B_bfin_rc,
    float* __restrict__ t_w0, float* __restrict__ t_b0, float* __restrict__ t_l1,
    float* __restrict__ t_bias1, float* __restrict__ t_fin, float* __restrict__ u2out) {
  int blk = blockIdx.x;
  int b = blk / 312;
  int tid = threadIdx.x, lane = tid & 63, wid = tid >> 6;
  int r = (blk % 312) * 4 + wid;
  __shared__ float rcs[1344];
  for (int i = tid; i < 1344; i += 256) rcs[i] = rc[b * 1344 + i];
  __syncthreads();
  const float* W; const float* Bb; float* dst; int row;
  if (r < 512)      { W = W_w0_rc;    Bb = B_w0_rc;    row = r;       dst = t_w0 + b * 512; }
  else if (r < 544) { W = W_b0_rc;    Bb = B_b0_rc;    row = r - 512; dst = t_b0 + b * 32; }
  else if (r < 576) { W = W_l1_rc;    Bb = B_l1_rc;    row = r - 544; dst = t_l1 + b * 32; }
  else if (r < 608) { W = W_bias1_rc; Bb = B_bias1_rc; row = r - 576; dst = t_bias1 + b * 32; }
  else if (r < 928) { W = W_fin_rc;   Bb = B_fin_rc;   row = r - 608; dst = t_fin + b * 320; }
  else              { W = W_bfin_rc;  Bb = B_bfin_rc;  row = r - 928; dst = u2out + b * 320; }
  const float* wr = W + (size_t)row * 1344;
  float acc = 0.f;
  for (int j = lane; j < 1344; j += 64) acc += wr[j] * rcs[j];
  acc = wave_reduce(acc);
  if (lane == 0) dst[row] = acc + Bb[row];
}

// ---- fused rterm / cterm+u1, 8 outputs per thread, weights LDS-staged ----
// grid (2, 8, 8): oy<4 -> rterm outputs o0=oy*8 ; oy>=4 -> cterm+u1 o0=(oy-4)*8
__global__ __launch_bounds__(256) void krcterm(
    const float* __restrict__ rm1, const float* __restrict__ cm0,
    const float* __restrict__ b0, const float* __restrict__ w0T,
    const float* __restrict__ W_l1_r, const float* __restrict__ B_l1_r,
    float* __restrict__ rterm,
    const float* __restrict__ cm1, const float* __restrict__ b1,
    const float* __restrict__ rm2, const float* __restrict__ w2,
    const float* __restrict__ W_l1_c, const float* __restrict__ B_l1_c,
    const float* __restrict__ B_l1, const float* __restrict__ t_l1,
    const float* __restrict__ W_bias1, const float* __restrict__ B_bias1,
    const float* __restrict__ t_bias1,
    float* __restrict__ cterm_full, float* __restrict__ u1out) {
  __shared__ float wlds[6656];  // max(608*8, 416*8*2) = 26 KB
  int oy = blockIdx.y, b = blockIdx.z;
  int tid = threadIdx.x;
  int p = blockIdx.x * 256 + tid;
  if (oy < 4) {
    int o0 = oy * 8;
    for (int idx = tid; idx < 608 * 8; idx += 256) {
      int i = idx >> 3, oo = idx & 7;
      wlds[idx] = W_l1_r[(size_t)(o0 + oo) * 608 + i];
    }
    __syncthreads();
    float acc[8] = {0, 0, 0, 0, 0, 0, 0, 0};
#pragma unroll 4
    for (int i = 0; i < 32; ++i) {
      float x = rm1[((size_t)b * 32 + i) * 512 + p] * (1.f / 512.f);
      float4 wa = *(const float4*)&wlds[i * 8];
      float4 wb = *(const float4*)&wlds[i * 8 + 4];
      acc[0] += wa.x * x; acc[1] += wa.y * x; acc[2] += wa.z * x; acc[3] += wa.w * x;
      acc[4] += wb.x * x; acc[5] += wb.y * x; acc[6] += wb.z * x; acc[7] += wb.w * x;
    }
#pragma unroll 4
    for (int i = 0; i < 32; ++i) {
      float x = cm0[((size_t)b * 32 + i) * 512 + p];
      float4 wa = *(const float4*)&wlds[(32 + i) * 8];
      float4 wb = *(const float4*)&wlds[(32 + i) * 8 + 4];
      acc[0] += wa.x * x; acc[1] += wa.y * x; acc[2] += wa.z * x; acc[3] += wa.w * x;
      acc[4] += wb.x * x; acc[5] += wb.y * x; acc[6] += wb.z * x; acc[7] += wb.w * x;
    }
#pragma unroll 4
    for (int i = 0; i < 32; ++i) {
      float x = b0[((size_t)b * 32 + i) * 512 + p];
      float4 wa = *(const float4*)&wlds[(64 + i) * 8];
      float4 wb = *(const float4*)&wlds[(64 + i) * 8 + 4];
      acc[0] += wa.x * x; acc[1] += wa.y * x; acc[2] += wa.z * x; acc[3] += wa.w * x;
      acc[4] += wb.x * x; acc[5] += wb.y * x; acc[6] += wb.z * x; acc[7] += wb.w * x;
    }
    const float* xp = w0T + (size_t)b * 512 * 512 + p;
#pragma unroll 4
    for (int i = 0; i < 512; ++i) {
      float x = xp[(size_t)i * 512];
      float4 wa = *(const float4*)&wlds[(96 + i) * 8];
      float4 wb = *(const float4*)&wlds[(96 + i) * 8 + 4];
      acc[0] += wa.x * x; acc[1] += wa.y * x; acc[2] += wa.z * x; acc[3] += wa.w * x;
      acc[4] += wb.x * x; acc[5] += wb.y * x; acc[6] += wb.z * x; acc[7] += wb.w * x;
    }
#pragma unroll
    for (int oo = 0; oo < 8; ++oo) {
      int o = o0 + oo;
      rterm[((size_t)b * 32 + o) * 512 + p] = acc[oo] + B_l1_r[o];
    }
  } else {
    int o0 = (oy - 4) * 8;
    for (int idx = tid; idx < 416 * 8; idx += 256) {
      int i = idx >> 3, oo = idx & 7;
      wlds[idx] = W_l1_c[(size_t)(o0 + oo) * 416 + i];
      wlds[3328 + idx] = W_bias1[(size_t)(o0 + oo) * 416 + i];
    }
    __syncthreads();
    float ac[8] = {0, 0, 0, 0, 0, 0, 0, 0};
    float au[8] = {0, 0, 0, 0, 0, 0, 0, 0};
#pragma unroll 4
    for (int i = 0; i < 32; ++i) {
      float x = cm1[((size_t)b * 32 + i) * 512 + p];
      float4 wa = *(const float4*)&wlds[i * 8];
      float4 wb = *(const float4*)&wlds[i * 8 + 4];
      float4 va = *(const float4*)&wlds[3328 + i * 8];
      float4 vb = *(const float4*)&wlds[3328 + i * 8 + 4];
      ac[0] += wa.x * x; ac[1] += wa.y * x; ac[2] += wa.z * x; ac[3] += wa.w * x;
      ac[4] += wb.x * x; ac[5] += wb.y * x; ac[6] += wb.z * x; ac[7] += wb.w * x;
      au[0] += va.x * x; au[1] += va.y * x; au[2] += va.z * x; au[3] += va.w * x;
      au[4] += vb.x * x; au[5] += vb.y * x; au[6] += vb.z * x; au[7] += vb.w * x;
    }
#pragma unroll 4
    for (int i = 0; i < 32; ++i) {
      float x = b1[((size_t)b * 32 + i) * 512 + p];
      float4 wa = *(const float4*)&wlds[(32 + i) * 8];
      float4 wb = *(const float4*)&wlds[(32 + i) * 8 + 4];
      float4 va = *(const float4*)&wlds[3328 + (32 + i) * 8];
      float4 vb = *(const float4*)&wlds[3328 + (32 + i) * 8 + 4];
      ac[0] += wa.x * x; ac[1] += wa.y * x; ac[2] += wa.z * x; ac[3] += wa.w * x;
      ac[4] += wb.x * x; ac[5] += wb.y * x; ac[6] += wb.z * x; ac[7] += wb.w * x;
      au[0] += va.x * x; au[1] += va.y * x; au[2] += va.z * x; au[3] += va.w * x;
      au[4] += vb.x * x; au[5] += vb.y * x; au[6] += vb.z * x; au[7] += vb.w * x;
    }
#pragma unroll 4
    for (int i = 0; i < 32; ++i) {
      float x = rm2[((size_t)b * 32 + i) * 512 + p];
      float4 wa = *(const float4*)&wlds[(64 + i) * 8];
      float4 wb = *(const float4*)&wlds[(64 + i) * 8 + 4];
      float4 va = *(const float4*)&wlds[3328 + (64 + i) * 8];
      float4 vb = *(const float4*)&wlds[3328 + (64 + i) * 8 + 4];
      ac[0] += wa.x * x; ac[1] += wa.y * x; ac[2] += wa.z * x; ac[3] += wa.w * x;
      ac[4] += wb.x * x; ac[5] += wb.y * x; ac[6] += wb.z * x; ac[7] += wb.w * x;
      au[0] += va.x * x; au[1] += va.y * x; au[2] += va.z * x; au[3] += va.w * x;
      au[4] += vb.x * x; au[5] += vb.y * x; au[6] += vb.z * x; au[7] += vb.w * x;
    }
    const float* xp = w2 + (size_t)b * 320 * 512 + p;
#pragma unroll 4
    for (int i = 0; i < 320; ++i) {
      float x = xp[(size_t)i * 512];
      float4 wa = *(const float4*)&wlds[(96 + i) * 8];
      float4 wb = *(const float4*)&wlds[(96 + i) * 8 + 4];
      float4 va = *(const float4*)&wlds[3328 + (96 + i) * 8];
      float4 vb = *(const float4*)&wlds[3328 + (96 + i) * 8 + 4];
      ac[0] += wa.x * x; ac[1] += wa.y * x; ac[2] += wa.z * x; ac[3] += wa.w * x;
      ac[4] += wb.x * x; ac[5] += wb.y * x; ac[6] += wb.z * x; ac[7] += wb.w * x;
      au[0] += va.x * x; au[1] += va.y * x; au[2] += va.z * x; au[3] += va.w * x;
      au[4] += vb.x * x; au[5] += vb.y * x; au[6] += vb.z * x; au[7] += vb.w * x;
    }
#pragma unroll
    for (int oo = 0; oo < 8; ++oo) {
      int o = o0 + oo;
      cterm_full[((size_t)b * 32 + o) * 512 + p] = ac[oo] + B_l1_c[o] + B_l1[o] + t_l1[b * 32 + o];
      u1out[((size_t)b * 32 + o) * 512 + p] = au[oo] + B_bias1[o] + t_bias1[b * 32 + o];
    }
  }
}

// ---- z0 (-> zw0) and u0: weights LDS-staged, 8 outputs/thread ----
__global__ __launch_bounds__(256) void kz0(
    const float* __restrict__ w0T, const float* __restrict__ rm1,
    const float* __restrict__ b0, const float* __restrict__ W_w0_rpt,
    const float* __restrict__ B_rpt, const float* __restrict__ W_b0,
    const float* __restrict__ B_b0w, const float* __restrict__ t_w0,
    const float* __restrict__ t_b0, float* __restrict__ out) {
  __shared__ float wlds[576 * 8];  // 18 KB
  int oc = blockIdx.y, b = blockIdx.z;
  int tid = threadIdx.x;
  bool isZ = oc < 64;
  int o0 = isZ ? oc * 8 : (oc - 64) * 8;
  const float* Wsrc = isZ ? W_w0_rpt : W_b0;  // both row-major with row length 576
  for (int idx = tid; idx < 576 * 8; idx += 256) {
    int i = idx >> 3, oo = idx & 7;
    wlds[idx] = Wsrc[(size_t)(o0 + oo) * 576 + i];
  }
  __syncthreads();
  int d = blockIdx.x * 256 + tid;
  float acc[8] = {0, 0, 0, 0, 0, 0, 0, 0};
  const float* xp = w0T + (size_t)b * 512 * 512 + d;
#pragma unroll 4
  for (int i = 0; i < 512; ++i) {
    float x = xp[(size_t)i * 512];
    float4 wa = *(const float4*)&wlds[i * 8];
    float4 wb = *(const float4*)&wlds[i * 8 + 4];
    acc[0] += wa.x * x; acc[1] += wa.y * x; acc[2] += wa.z * x; acc[3] += wa.w * x;
    acc[4] += wb.x * x; acc[5] += wb.y * x; acc[6] += wb.z * x; acc[7] += wb.w * x;
  }
#pragma unroll 4
  for (int i = 0; i < 32; ++i) {
    float x = rm1[((size_t)b * 32 + i) * 512 + d] * (1.f / 512.f);
    float4 wa = *(const float4*)&wlds[(512 + i) * 8];
    float4 wb = *(const float4*)&wlds[(512 + i) * 8 + 4];
    acc[0] += wa.x * x; acc[1] += wa.y * x; acc[2] += wa.z * x; acc[3] += wa.w * x;
    acc[4] += wb.x * x; acc[5] += wb.y * x; acc[6] += wb.z * x; acc[7] += wb.w * x;
  }
#pragma unroll 4
  for (int i = 0; i < 32; ++i) {
    float x = b0[((size_t)b * 32 + i) * 512 + d];
    float4 wa = *(const float4*)&wlds[(544 + i) * 8];
    float4 wb = *(const float4*)&wlds[(544 + i) * 8 + 4];
    acc[0] += wa.x * x; acc[1] += wa.y * x; acc[2] += wa.z * x; acc[3] += wa.w * x;
    acc[4] += wb.x * x; acc[5] += wb.y * x; acc[6] += wb.z * x; acc[7] += wb.w * x;
  }
  if (isZ) {
#pragma unroll
    for (int oo = 0; oo < 8; ++oo) {
      int o = o0 + oo, co = o >> 4, k = o & 15;
      out[(((size_t)b * 32 + co) * 512 + d) * 16 + k] = acc[oo] + B_rpt[o] + t_w0[b * 512 + o];
    }
  } else {
#pragma unroll
    for (int oo = 0; oo < 8; ++oo) {
      int o = o0 + oo;
      out[OUT_U0 + ((size_t)b * 32 + o) * 512 + d] = acc[oo] + B_b0w[o] + t_b0[b * 32 + o];
    }
  }
}

// ---- zf -> zw2: weights LDS-staged ----
__global__ __launch_bounds__(256) void kzf(
    const float* __restrict__ w2, const float* __restrict__ cm1,
    const float* __restrict__ W_fin_cpt, const float* __restrict__ B_fin,
    const float* __restrict__ t_fin, float* __restrict__ out) {
  __shared__ float wlds[352 * 8];  // 11 KB
  int oc = blockIdx.y, b = blockIdx.z;
  int tid = threadIdx.x;
  int o0 = oc * 8;
  for (int idx = tid; idx < 352 * 8; idx += 256) {
    int i = idx >> 3, oo = idx & 7;
    wlds[idx] = W_fin_cpt[(size_t)(o0 + oo) * 352 + i];
  }
  __syncthreads();
  int d = blockIdx.x * 256 + tid;
  float acc[8] = {0, 0, 0, 0, 0, 0, 0, 0};
  const float* xp = w2 + (size_t)b * 320 * 512 + d;
#pragma unroll 4
  for (int i = 0; i < 320; ++i) {
    float x = xp[(size_t)i * 512];
    float4 wa = *(const float4*)&wlds[i * 8];
    float4 wb = *(const float4*)&wlds[i * 8 + 4];
    acc[0] += wa.x * x; acc[1] += wa.y * x; acc[2] += wa.z * x; acc[3] += wa.w * x;
    acc[4] += wb.x * x; acc[5] += wb.y * x; acc[6] += wb.z * x; acc[7] += wb.w * x;
  }
#pragma unroll 4
  for (int i = 0; i < 32; ++i) {
    float x = cm1[((size_t)b * 32 + i) * 512 + d];
    float4 wa = *(const float4*)&wlds[(320 + i) * 8];
    float4 wb = *(const float4*)&wlds[(320 + i) * 8 + 4];
    acc[0] += wa.x * x; acc[1] += wa.y * x; acc[2] += wa.z * x; acc[3] += wa.w * x;
    acc[4] += wb.x * x; acc[5] += wb.y * x; acc[6] += wb.z * x; acc[7] += wb.w * x;
  }
#pragma unroll
  for (int oo = 0; oo < 8; ++oo) {
    int o = o0 + oo;
    out[OUT_ZW2 + ((size_t)b * 320 + o) * 512 + d] = acc[oo] + B_fin[o] + t_fin[b * 320 + o];
  }
}

// ---- zw1: float4, 2 rows per block. grid (256, 8) ----
__global__ __launch_bounds__(256) void kzw1(
    const float* __restrict__ w1, const float* __restrict__ Wt_l1,
    const float* __restrict__ rterm, const float* __restrict__ cterm,
    float* __restrict__ out) {
  int hp = blockIdx.x, b = blockIdx.y;
  int t = threadIdx.x;
  int h0 = hp * 2;
  int hoff = t >> 7;           // 0 or 1
  int w = (t & 127) * 4;       // 0..508
  float4 acc[32];
#pragma unroll
  for (int o = 0; o < 32; ++o) acc[o] = make_float4(0.f, 0.f, 0.f, 0.f);
  const float* src = w1 + ((size_t)b * 32 * 512 + h0) * 512 + 4 * t;  // 4t = hoff*512 + w
#pragma unroll 4
  for (int i = 0; i < 32; ++i) {
    float4 x = *(const float4*)(src + (size_t)i * 262144);
    const float* wp = Wt_l1 + i * 32;
#pragma unroll
    for (int o = 0; o < 32; ++o) {
      acc[o].x += wp[o] * x.x;
      acc[o].y += wp[o] * x.y;
      acc[o].z += wp[o] * x.z;
      acc[o].w += wp[o] * x.w;
    }
  }
  int h = h0 + hoff;
#pragma unroll
  for (int o = 0; o < 32; ++o) {
    float cf = cterm[((size_t)b * 32 + o) * 512 + h];
    float4 rt = *(const float4*)(rterm + ((size_t)b * 32 + o) * 512 + w);
    float4 res = make_float4(acc[o].x + rt.x + cf, acc[o].y + rt.y + cf,
                             acc[o].z + rt.z + cf, acc[o].w + rt.w + cf);
    *(float4*)(out + (size_t)OUT_ZW1 + (((size_t)b * 32 + o) * 512 + h) * 512 + w) = res;
  }
}

extern "C" void kernel_launch(void* const* d_in, const int* in_sizes, int n_in,
                              void* d_out, int out_size, void* d_ws, size_t ws_size,
                              hipStream_t stream) {
  const float* w0 = (const float*)d_in[0];
  const float* w1 = (const float*)d_in[1];
  const float* w2 = (const float*)d_in[2];
  const float* b0 = (const float*)d_in[3];
  const float* b1 = (const float*)d_in[4];
  const float* b2 = (const float*)d_in[5];
  const float* W_w0_rpt = (const float*)d_in[6];
  const float* B_w0_rpt = (const float*)d_in[7];
  const float* W_w0_rc = (const float*)d_in[8];
  const float* B_w0_rc = (const float*)d_in[9];
  const float* W_b0 = (const float*)d_in[10];
  const float* B_b0 = (const float*)d_in[11];
  const float* W_b0_rc = (const float*)d_in[12];
  const float* B_b0_rc = (const float*)d_in[13];
  const float* W_l1 = (const float*)d_in[14];
  const float* B_l1 = (const float*)d_in[15];
  const float* W_l1_rc = (const float*)d_in[16];
  const float* B_l1_rc = (const float*)d_in[17];
  const float* W_l1_r = (const float*)d_in[18];
  const float* B_l1_r = (const float*)d_in[19];
  const float* W_l1_c = (const float*)d_in[20];
  const float* B_l1_c = (const float*)d_in[21];
  const float* W_bias1 = (const float*)d_in[22];
  const float* B_bias1 = (const float*)d_in[23];
  const float* W_bias1_rc = (const float*)d_in[24];
  const float* B_bias1_rc = (const float*)d_in[25];
  const float* W_fin_cpt = (const float*)d_in[26];
  const float* B_fin_cpt = (const float*)d_in[27];
  const float* W_fin_rc = (const float*)d_in[28];
  const float* B_fin_rc = (const float*)d_in[29];
  const float* W_bfin_rc = (const float*)d_in[30];
  const float* B_bfin_rc = (const float*)d_in[31];
  float* ws = (float*)d_ws;
  float* out = (float*)d_out;

  kprep<<<dim3(814), 256, 0, stream>>>(w0, W_l1, ws);

  kstats<<<dim3(256), 256, 0, stream>>>(w0, w2, b0, b1, b2, ws + WS_CM0, ws + WS_RM2,
                                        ws + WS_CM2, ws + WS_RC);
  kw1stats<<<dim3(1024), 256, 0, stream>>>(w1, ws + WS_RM1, ws + WS_CM1, ws + WS_RC);

  krcgemm<<<dim3(8 * 312), 256, 0, stream>>>(
      ws + WS_RC, W_w0_rc, B_w0_rc, W_b0_rc, B_b0_rc, W_l1_rc, B_l1_rc, W_bias1_rc,
      B_bias1_rc, W_fin_rc, B_fin_rc, W_bfin_rc, B_bfin_rc, ws + WS_TW0, ws + WS_TB0,
      ws + WS_TL1, ws + WS_TBIAS1, ws + WS_TFIN, out + OUT_U2);

  krcterm<<<dim3(2, 8, 8), 256, 0, stream>>>(
      ws + WS_RM1, ws + WS_CM0, b0, ws + WS_W0T, W_l1_r, B_l1_r, ws + WS_RTERM,
      ws + WS_CM1, b1, ws + WS_RM2, w2, W_l1_c, B_l1_c, B_l1, ws + WS_TL1, W_bias1,
      B_bias1, ws + WS_TBIAS1, ws + WS_CTERM, out + OUT_U1);

  kz0<<<dim3(2, 68, 8), 256, 0, stream>>>(ws + WS_W0T, ws + WS_RM1, b0, W_w0_rpt,
                                          B_w0_rpt, W_b0, B_b0, ws + WS_TW0,
                                          ws + WS_TB0, out);
  kzf<<<dim3(2, 40, 8), 256, 0, stream>>>(w2, ws + WS_CM1, W_fin_cpt, B_fin_cpt,
                                          ws + WS_TFIN, out);
  kzw1<<<dim3(256, 8), 256, 0, stream>>>(w1, ws + WS_WT_L1, ws + WS_RTERM, ws + WS_CTERM,
                                         out);
  (void)in_sizes; (void)n_in; (void)out_size; (void)ws_size;
}

// Round 5
// 364.641 us; speedup vs baseline: 1.4011x; 1.1575x over previous
//
#include <hip/hip_runtime.h>

// ---------------- constants ----------------
// B=8, C=32, CO=32, NIN=16, NOUT=10, D1=D2=512, NRC=1344
// outputs (fp32, concatenated): zw0[8,32,512,16] zw1[8,32,512,512] zw2[8,32,10,512]
//                               u0[8,32,512] u1[8,32,512] u2[8,32,10]
#define OUT_ZW1 2097152u
#define OUT_ZW2 69206016u
#define OUT_U0  70516736u
#define OUT_U1  70647808u
#define OUT_U2  70778880u

// workspace layout (floats)
#define WS_RM1      0u        // raw col-sums of w1 (normalize by 1/512 at use)
#define WS_CM1      131072u
#define WS_CM0      262144u
#define WS_RM2      393216u
#define WS_CM2      524288u
#define WS_RC       526848u
#define WS_TW0      537600u
#define WS_TB0      541696u
#define WS_TL1      541952u
#define WS_TBIAS1   542208u
#define WS_TFIN     542464u
#define WS_RTERM    545024u
#define WS_CTERM    676096u
#define WS_W0T      807168u
#define WS_WT_L1    3330304u

static __device__ __forceinline__ float wave_reduce(float v) {
#pragma unroll
  for (int off = 32; off > 0; off >>= 1) v += __shfl_down(v, off);
  return v;
}

// ---- fused setup: zero atomic targets + W_l1 transpose + w0 transpose ----
// block ranges: [0,554) zero | [554,558) W_l1^T | [558,814) w0T
__global__ __launch_bounds__(256) void kprep(
    const float* __restrict__ w0, const float* __restrict__ W_l1,
    float* __restrict__ ws) {
  int blk = blockIdx.x, tid = threadIdx.x;
  if (blk < 554) {
    int i = blk * 256 + tid;  // 141824 = 554*256 exactly
    if (i < 131072) ws[WS_RM1 + i] = 0.f;
    else ws[WS_RC + (i - 131072)] = 0.f;
  } else if (blk < 558) {
    int idx = (blk - 554) * 256 + tid;          // 1024: (32,32)
    int r = idx >> 5, c = idx & 31;
    ws[WS_WT_L1 + c * 32 + r] = W_l1[idx];
  } else {
    int bc = blk - 558;                         // 256 blocks: w0 -> w0T
    int b = bc >> 5, c = bc & 31;
    for (int k = 0; k < 16; ++k)
      for (int d = tid; d < 512; d += 256)
        ws[WS_W0T + ((size_t)(b * 512 + c * 16 + k)) * 512 + d] =
            w0[((size_t)bc * 512 + d) * 16 + k];
  }
}

// ---- merged small stats (blocks [0,256)) + w1 stats (blocks [256,1280)) ----
__global__ __launch_bounds__(256) void kstats2(
    const float* __restrict__ w0, const float* __restrict__ w2,
    const float* __restrict__ b0, const float* __restrict__ b1,
    const float* __restrict__ b2, const float* __restrict__ w1,
    float* __restrict__ cm0, float* __restrict__ rm2, float* __restrict__ cm2,
    float* __restrict__ rm1, float* __restrict__ cm1, float* __restrict__ rc) {
  __shared__ float sred[16];
  __shared__ float stot;
  __shared__ float rpart[512];
  int tid = threadIdx.x, lane = tid & 63;

  if (blockIdx.x < 256) {
    int bc = blockIdx.x;
    int b = bc >> 5, c = bc & 31;
    float* rcb = rc + b * 1344;

    if (tid < 16) sred[tid] = 0.f;
    if (tid == 0) stot = 0.f;
    __syncthreads();
    {
      float rm0p[16];
#pragma unroll
      for (int k = 0; k < 16; ++k) rm0p[k] = 0.f;
      float tot = 0.f;
      for (int d = tid; d < 512; d += 256) {
        const float4* p = (const float4*)(w0 + ((size_t)bc * 512 + d) * 16);
        float s = 0.f;
#pragma unroll
        for (int q = 0; q < 4; ++q) {
          float4 v = p[q];
          s += v.x + v.y + v.z + v.w;
          rm0p[q * 4 + 0] += v.x; rm0p[q * 4 + 1] += v.y;
          rm0p[q * 4 + 2] += v.z; rm0p[q * 4 + 3] += v.w;
        }
        cm0[(size_t)bc * 512 + d] = s * (1.f / 16.f);
        tot += s;
      }
#pragma unroll
      for (int k = 0; k < 16; ++k) {
        float r = wave_reduce(rm0p[k]);
        if (lane == 0) atomicAdd(&sred[k], r);
      }
      float rt = wave_reduce(tot);
      if (lane == 0) atomicAdd(&stot, rt);
    }
    __syncthreads();
    if (tid < 16) rcb[192 + c * 16 + tid] = sred[tid] * (1.f / 512.f);
    if (tid == 0) rcb[c] = stot * (1.f / 8192.f);
    __syncthreads();

    if (tid < 10) sred[tid] = 0.f;
    if (tid == 0) stot = 0.f;
    __syncthreads();
    {
      float cm2p[10];
#pragma unroll
      for (int k = 0; k < 10; ++k) cm2p[k] = 0.f;
      float tot = 0.f;
      for (int d = tid; d < 512; d += 256) {
        float s = 0.f;
#pragma unroll
        for (int k = 0; k < 10; ++k) {
          float v = w2[((size_t)bc * 10 + k) * 512 + d];
          s += v; cm2p[k] += v;
        }
        rm2[(size_t)bc * 512 + d] = s * 0.1f;
        tot += s;
      }
#pragma unroll
      for (int k = 0; k < 10; ++k) {
        float r = wave_reduce(cm2p[k]);
        if (lane == 0) atomicAdd(&sred[k], r);
      }
      float rt = wave_reduce(tot);
      if (lane == 0) atomicAdd(&stot, rt);
    }
    __syncthreads();
    if (tid < 10) {
      float m = sred[tid] * (1.f / 512.f);
      cm2[bc * 10 + tid] = m;
      rcb[704 + c * 10 + tid] = m;
    }
    if (tid == 0) rcb[64 + c] = stot * (1.f / 5120.f);
    __syncthreads();

    if (tid < 2) sred[tid] = 0.f;
    __syncthreads();
    {
      float t0 = 0.f, t1 = 0.f;
      for (int d = tid; d < 512; d += 256) {
        t0 += b0[(size_t)bc * 512 + d];
        t1 += b1[(size_t)bc * 512 + d];
      }
      t0 = wave_reduce(t0); t1 = wave_reduce(t1);
      if (lane == 0) { atomicAdd(&sred[0], t0); atomicAdd(&sred[1], t1); }
    }
    __syncthreads();
    if (tid == 0) {
      rcb[96 + c] = sred[0] * (1.f / 512.f);
      rcb[128 + c] = sred[1] * (1.f / 512.f);
    }

    float vb2 = 0.f;
    if (tid < 10) {
      vb2 = b2[bc * 10 + tid];
      rcb[1024 + c * 10 + tid] = vb2;
    }
    if (tid < 64) {
      float s = wave_reduce(vb2);
      if (tid == 0) rcb[160 + c] = s * 0.1f;
    }
  } else {
    int idx = blockIdx.x - 256;
    int bc = idx >> 2, hc = idx & 3;
    int b = bc >> 5, c = bc & 31;
    int wid = tid >> 6;
    const float* base = w1 + (size_t)bc * 262144 + (size_t)hc * 128 * 512;
    float col0 = 0.f, col1 = 0.f;
    for (int hl = 0; hl < 128; ++hl) {
      float2 x = *(const float2*)(base + hl * 512 + 2 * tid);
      col0 += x.x; col1 += x.y;
      float r = wave_reduce(x.x + x.y);
      if (lane == 0) rpart[hl * 4 + wid] = r;
    }
    __syncthreads();
    if (tid < 128) {
      float s = rpart[tid * 4] + rpart[tid * 4 + 1] + rpart[tid * 4 + 2] + rpart[tid * 4 + 3];
      cm1[(size_t)bc * 512 + hc * 128 + tid] = s * (1.f / 512.f);
    }
    atomicAdd(&rm1[(size_t)bc * 512 + 2 * tid], col0);
    atomicAdd(&rm1[(size_t)bc * 512 + 2 * tid + 1], col1);
    float bt = wave_reduce(col0 + col1);
    if (lane == 0) atomicAdd(&rc[b * 1344 + 32 + c], bt * (1.f / 262144.f));
  }
}

__global__ __launch_bounds__(256) void krcgemm(
    const float* __restrict__ rc,
    const float* __restrict__ W_w0_rc, const float* __restrict__ B_w0_rc,
    const float* __restrict__ W_b0_rc, const float* __restrict__ B_b0_rc,
    const float* __restrict__ W_l1_rc, const float* __restrict__ B_l1_rc,
    const float* __restrict__ W_bias1_rc, const float* __restrict__ B_bias1_rc,
    const float* __restrict__ W_fin_rc, const float* __restrict__ B_fin_rc,
    const float* __restrict__ W_bfin_rc, const float* __restrict__ B_bfin_rc,
    float* __restrict__ t_w0, float* __restrict__ t_b0, float* __restrict__ t_l1,
    float* __restrict__ t_bias1, float* __restrict__ t_fin, float* __restrict__ u2out) {
  int blk = blockIdx.x;
  int b = blk / 312;
  int tid = threadIdx.x, lane = tid & 63, wid = tid >> 6;
  int r = (blk % 312) * 4 + wid;
  __shared__ float rcs[1344];
  for (int i = tid; i < 1344; i += 256) rcs[i] = rc[b * 1344 + i];
  __syncthreads();
  const float* W; const float* Bb; float* dst; int row;
  if (r < 512)      { W = W_w0_rc;    Bb = B_w0_rc;    row = r;       dst = t_w0 + b * 512; }
  else if (r < 544) { W = W_b0_rc;    Bb = B_b0_rc;    row = r - 512; dst = t_b0 + b * 32; }
  else if (r < 576) { W = W_l1_rc;    Bb = B_l1_rc;    row = r - 544; dst = t_l1 + b * 32; }
  else if (r < 608) { W = W_bias1_rc; Bb = B_bias1_rc; row = r - 576; dst = t_bias1 + b * 32; }
  else if (r < 928) { W = W_fin_rc;   Bb = B_fin_rc;   row = r - 608; dst = t_fin + b * 320; }
  else              { W = W_bfin_rc;  Bb = B_bfin_rc;  row = r - 928; dst = u2out + b * 320; }
  const float* wr = W + (size_t)row * 1344;
  float acc = 0.f;
  for (int j = lane; j < 1344; j += 64) acc += wr[j] * rcs[j];
  acc = wave_reduce(acc);
  if (lane == 0) dst[row] = acc + Bb[row];
}

// ---- merged mid-size GEMMs: krcterm [0,128) | kz0 [128,1216) | kzf [1216,1856) ----
__global__ __launch_bounds__(256) void kbig(
    const float* __restrict__ rm1, const float* __restrict__ cm0,
    const float* __restrict__ b0, const float* __restrict__ w0T,
    const float* __restrict__ W_l1_r, const float* __restrict__ B_l1_r,
    float* __restrict__ rterm,
    const float* __restrict__ cm1, const float* __restrict__ b1,
    const float* __restrict__ rm2, const float* __restrict__ w2,
    const float* __restrict__ W_l1_c, const float* __restrict__ B_l1_c,
    const float* __restrict__ B_l1, const float* __restrict__ t_l1,
    const float* __restrict__ W_bias1, const float* __restrict__ B_bias1,
    const float* __restrict__ t_bias1,
    float* __restrict__ cterm_full, float* __restrict__ u1out,
    const float* __restrict__ W_w0_rpt, const float* __restrict__ B_rpt,
    const float* __restrict__ W_b0, const float* __restrict__ B_b0w,
    const float* __restrict__ t_w0, const float* __restrict__ t_b0,
    const float* __restrict__ W_fin_cpt, const float* __restrict__ B_fin,
    const float* __restrict__ t_fin, float* __restrict__ out) {
  __shared__ float wlds[6656];  // 26 KB
  int bid = blockIdx.x, tid = threadIdx.x;

  if (bid < 128) {
    // ======== krcterm: x = bid&1, oy = (bid>>1)&7, b = bid>>4 ========
    int x = bid & 1, oy = (bid >> 1) & 7, b = bid >> 4;
    int p = x * 256 + tid;
    if (oy < 4) {
      int o0 = oy * 8;
      for (int idx = tid; idx < 608 * 8; idx += 256) {
        int i = idx >> 3, oo = idx & 7;
        wlds[idx] = W_l1_r[(size_t)(o0 + oo) * 608 + i];
      }
      __syncthreads();
      float acc[8] = {0, 0, 0, 0, 0, 0, 0, 0};
#pragma unroll 4
      for (int i = 0; i < 32; ++i) {
        float xv = rm1[((size_t)b * 32 + i) * 512 + p] * (1.f / 512.f);
        float4 wa = *(const float4*)&wlds[i * 8];
        float4 wb = *(const float4*)&wlds[i * 8 + 4];
        acc[0] += wa.x * xv; acc[1] += wa.y * xv; acc[2] += wa.z * xv; acc[3] += wa.w * xv;
        acc[4] += wb.x * xv; acc[5] += wb.y * xv; acc[6] += wb.z * xv; acc[7] += wb.w * xv;
      }
#pragma unroll 4
      for (int i = 0; i < 32; ++i) {
        float xv = cm0[((size_t)b * 32 + i) * 512 + p];
        float4 wa = *(const float4*)&wlds[(32 + i) * 8];
        float4 wb = *(const float4*)&wlds[(32 + i) * 8 + 4];
        acc[0] += wa.x * xv; acc[1] += wa.y * xv; acc[2] += wa.z * xv; acc[3] += wa.w * xv;
        acc[4] += wb.x * xv; acc[5] += wb.y * xv; acc[6] += wb.z * xv; acc[7] += wb.w * xv;
      }
#pragma unroll 4
      for (int i = 0; i < 32; ++i) {
        float xv = b0[((size_t)b * 32 + i) * 512 + p];
        float4 wa = *(const float4*)&wlds[(64 + i) * 8];
        float4 wb = *(const float4*)&wlds[(64 + i) * 8 + 4];
        acc[0] += wa.x * xv; acc[1] += wa.y * xv; acc[2] += wa.z * xv; acc[3] += wa.w * xv;
        acc[4] += wb.x * xv; acc[5] += wb.y * xv; acc[6] += wb.z * xv; acc[7] += wb.w * xv;
      }
      const float* xp = w0T + (size_t)b * 512 * 512 + p;
#pragma unroll 4
      for (int i = 0; i < 512; ++i) {
        float xv = xp[(size_t)i * 512];
        float4 wa = *(const float4*)&wlds[(96 + i) * 8];
        float4 wb = *(const float4*)&wlds[(96 + i) * 8 + 4];
        acc[0] += wa.x * xv; acc[1] += wa.y * xv; acc[2] += wa.z * xv; acc[3] += wa.w * xv;
        acc[4] += wb.x * xv; acc[5] += wb.y * xv; acc[6] += wb.z * xv; acc[7] += wb.w * xv;
      }
#pragma unroll
      for (int oo = 0; oo < 8; ++oo) {
        int o = o0 + oo;
        rterm[((size_t)b * 32 + o) * 512 + p] = acc[oo] + B_l1_r[o];
      }
    } else {
      int o0 = (oy - 4) * 8;
      for (int idx = tid; idx < 416 * 8; idx += 256) {
        int i = idx >> 3, oo = idx & 7;
        wlds[idx] = W_l1_c[(size_t)(o0 + oo) * 416 + i];
        wlds[3328 + idx] = W_bias1[(size_t)(o0 + oo) * 416 + i];
      }
      __syncthreads();
      float ac[8] = {0, 0, 0, 0, 0, 0, 0, 0};
      float au[8] = {0, 0, 0, 0, 0, 0, 0, 0};
#pragma unroll 4
      for (int i = 0; i < 32; ++i) {
        float xv = cm1[((size_t)b * 32 + i) * 512 + p];
        float4 wa = *(const float4*)&wlds[i * 8];
        float4 wb = *(const float4*)&wlds[i * 8 + 4];
        float4 va = *(const float4*)&wlds[3328 + i * 8];
        float4 vb = *(const float4*)&wlds[3328 + i * 8 + 4];
        ac[0] += wa.x * xv; ac[1] += wa.y * xv; ac[2] += wa.z * xv; ac[3] += wa.w * xv;
        ac[4] += wb.x * xv; ac[5] += wb.y * xv; ac[6] += wb.z * xv; ac[7] += wb.w * xv;
        au[0] += va.x * xv; au[1] += va.y * xv; au[2] += va.z * xv; au[3] += va.w * xv;
        au[4] += vb.x * xv; au[5] += vb.y * xv; au[6] += vb.z * xv; au[7] += vb.w * xv;
      }
#pragma unroll 4
      for (int i = 0; i < 32; ++i) {
        float xv = b1[((size_t)b * 32 + i) * 512 + p];
        float4 wa = *(const float4*)&wlds[(32 + i) * 8];
        float4 wb = *(const float4*)&wlds[(32 + i) * 8 + 4];
        float4 va = *(const float4*)&wlds[3328 + (32 + i) * 8];
        float4 vb = *(const float4*)&wlds[3328 + (32 + i) * 8 + 4];
        ac[0] += wa.x * xv; ac[1] += wa.y * xv; ac[2] += wa.z * xv; ac[3] += wa.w * xv;
        ac[4] += wb.x * xv; ac[5] += wb.y * xv; ac[6] += wb.z * xv; ac[7] += wb.w * xv;
        au[0] += va.x * xv; au[1] += va.y * xv; au[2] += va.z * xv; au[3] += va.w * xv;
        au[4] += vb.x * xv; au[5] += vb.y * xv; au[6] += vb.z * xv; au[7] += vb.w * xv;
      }
#pragma unroll 4
      for (int i = 0; i < 32; ++i) {
        float xv = rm2[((size_t)b * 32 + i) * 512 + p];
        float4 wa = *(const float4*)&wlds[(64 + i) * 8];
        float4 wb = *(const float4*)&wlds[(64 + i) * 8 + 4];
        float4 va = *(const float4*)&wlds[3328 + (64 + i) * 8];
        float4 vb = *(const float4*)&wlds[3328 + (64 + i) * 8 + 4];
        ac[0] += wa.x * xv; ac[1] += wa.y * xv; ac[2] += wa.z * xv; ac[3] += wa.w * xv;
        ac[4] += wb.x * xv; ac[5] += wb.y * xv; ac[6] += wb.z * xv; ac[7] += wb.w * xv;
        au[0] += va.x * xv; au[1] += va.y * xv; au[2] += va.z * xv; au[3] += va.w * xv;
        au[4] += vb.x * xv; au[5] += vb.y * xv; au[6] += vb.z * xv; au[7] += vb.w * xv;
      }
      const float* xp = w2 + (size_t)b * 320 * 512 + p;
#pragma unroll 4
      for (int i = 0; i < 320; ++i) {
        float xv = xp[(size_t)i * 512];
        float4 wa = *(const float4*)&wlds[(96 + i) * 8];
        float4 wb = *(const float4*)&wlds[(96 + i) * 8 + 4];
        float4 va = *(const float4*)&wlds[3328 + (96 + i) * 8];
        float4 vb = *(const float4*)&wlds[3328 + (96 + i) * 8 + 4];
        ac[0] += wa.x * xv; ac[1] += wa.y * xv; ac[2] += wa.z * xv; ac[3] += wa.w * xv;
        ac[4] += wb.x * xv; ac[5] += wb.y * xv; ac[6] += wb.z * xv; ac[7] += wb.w * xv;
        au[0] += va.x * xv; au[1] += va.y * xv; au[2] += va.z * xv; au[3] += va.w * xv;
        au[4] += vb.x * xv; au[5] += vb.y * xv; au[6] += vb.z * xv; au[7] += vb.w * xv;
      }
#pragma unroll
      for (int oo = 0; oo < 8; ++oo) {
        int o = o0 + oo;
        cterm_full[((size_t)b * 32 + o) * 512 + p] = ac[oo] + B_l1_c[o] + B_l1[o] + t_l1[b * 32 + o];
        u1out[((size_t)b * 32 + o) * 512 + p] = au[oo] + B_bias1[o] + t_bias1[b * 32 + o];
      }
    }
  } else if (bid < 1216) {
    // ======== kz0: t = bid-128; x = t&1, rest = t>>1; oc = rest%68, b = rest/68 ========
    int t = bid - 128;
    int x = t & 1, rest = t >> 1;
    int oc = rest % 68, b = rest / 68;
    bool isZ = oc < 64;
    int o0 = isZ ? oc * 8 : (oc - 64) * 8;
    const float* Wsrc = isZ ? W_w0_rpt : W_b0;
    for (int idx = tid; idx < 576 * 8; idx += 256) {
      int i = idx >> 3, oo = idx & 7;
      wlds[idx] = Wsrc[(size_t)(o0 + oo) * 576 + i];
    }
    __syncthreads();
    int d = x * 256 + tid;
    float acc[8] = {0, 0, 0, 0, 0, 0, 0, 0};
    const float* xp = w0T + (size_t)b * 512 * 512 + d;
#pragma unroll 4
    for (int i = 0; i < 512; ++i) {
      float xv = xp[(size_t)i * 512];
      float4 wa = *(const float4*)&wlds[i * 8];
      float4 wb = *(const float4*)&wlds[i * 8 + 4];
      acc[0] += wa.x * xv; acc[1] += wa.y * xv; acc[2] += wa.z * xv; acc[3] += wa.w * xv;
      acc[4] += wb.x * xv; acc[5] += wb.y * xv; acc[6] += wb.z * xv; acc[7] += wb.w * xv;
    }
#pragma unroll 4
    for (int i = 0; i < 32; ++i) {
      float xv = rm1[((size_t)b * 32 + i) * 512 + d] * (1.f / 512.f);
      float4 wa = *(const float4*)&wlds[(512 + i) * 8];
      float4 wb = *(const float4*)&wlds[(512 + i) * 8 + 4];
      acc[0] += wa.x * xv; acc[1] += wa.y * xv; acc[2] += wa.z * xv; acc[3] += wa.w * xv;
      acc[4] += wb.x * xv; acc[5] += wb.y * xv; acc[6] += wb.z * xv; acc[7] += wb.w * xv;
    }
#pragma unroll 4
    for (int i = 0; i < 32; ++i) {
      float xv = b0[((size_t)b * 32 + i) * 512 + d];
      float4 wa = *(const float4*)&wlds[(544 + i) * 8];
      float4 wb = *(const float4*)&wlds[(544 + i) * 8 + 4];
      acc[0] += wa.x * xv; acc[1] += wa.y * xv; acc[2] += wa.z * xv; acc[3] += wa.w * xv;
      acc[4] += wb.x * xv; acc[5] += wb.y * xv; acc[6] += wb.z * xv; acc[7] += wb.w * xv;
    }
    if (isZ) {
#pragma unroll
      for (int oo = 0; oo < 8; ++oo) {
        int o = o0 + oo, co = o >> 4, k = o & 15;
        out[(((size_t)b * 32 + co) * 512 + d) * 16 + k] = acc[oo] + B_rpt[o] + t_w0[b * 512 + o];
      }
    } else {
#pragma unroll
      for (int oo = 0; oo < 8; ++oo) {
        int o = o0 + oo;
        out[OUT_U0 + ((size_t)b * 32 + o) * 512 + d] = acc[oo] + B_b0w[o] + t_b0[b * 32 + o];
      }
    }
  } else {
    // ======== kzf: t = bid-1216; x = t&1, rest = t>>1; oc = rest%40, b = rest/40 ========
    int t = bid - 1216;
    int x = t & 1, rest = t >> 1;
    int oc = rest % 40, b = rest / 40;
    int o0 = oc * 8;
    for (int idx = tid; idx < 352 * 8; idx += 256) {
      int i = idx >> 3, oo = idx & 7;
      wlds[idx] = W_fin_cpt[(size_t)(o0 + oo) * 352 + i];
    }
    __syncthreads();
    int d = x * 256 + tid;
    float acc[8] = {0, 0, 0, 0, 0, 0, 0, 0};
    const float* xp = w2 + (size_t)b * 320 * 512 + d;
#pragma unroll 4
    for (int i = 0; i < 320; ++i) {
      float xv = xp[(size_t)i * 512];
      float4 wa = *(const float4*)&wlds[i * 8];
      float4 wb = *(const float4*)&wlds[i * 8 + 4];
      acc[0] += wa.x * xv; acc[1] += wa.y * xv; acc[2] += wa.z * xv; acc[3] += wa.w * xv;
      acc[4] += wb.x * xv; acc[5] += wb.y * xv; acc[6] += wb.z * xv; acc[7] += wb.w * xv;
    }
#pragma unroll 4
    for (int i = 0; i < 32; ++i) {
      float xv = cm1[((size_t)b * 32 + i) * 512 + d];
      float4 wa = *(const float4*)&wlds[(320 + i) * 8];
      float4 wb = *(const float4*)&wlds[(320 + i) * 8 + 4];
      acc[0] += wa.x * xv; acc[1] += wa.y * xv; acc[2] += wa.z * xv; acc[3] += wa.w * xv;
      acc[4] += wb.x * xv; acc[5] += wb.y * xv; acc[6] += wb.z * xv; acc[7] += wb.w * xv;
    }
#pragma unroll
    for (int oo = 0; oo < 8; ++oo) {
      int o = o0 + oo;
      out[OUT_ZW2 + ((size_t)b * 320 + o) * 512 + d] = acc[oo] + B_fin[o] + t_fin[b * 320 + o];
    }
  }
}

// ---- zw1: float4, 2 rows per block, Wt_l1 LDS-staged. grid (256, 8) ----
__global__ __launch_bounds__(256) void kzw1(
    const float* __restrict__ w1, const float* __restrict__ Wt_l1,
    const float* __restrict__ rterm, const float* __restrict__ cterm,
    float* __restrict__ out) {
  __shared__ float wl[1024];
  int hp = blockIdx.x, b = blockIdx.y;
  int t = threadIdx.x;
  for (int i = t; i < 1024; i += 256) wl[i] = Wt_l1[i];
  __syncthreads();
  int h0 = hp * 2;
  int hoff = t >> 7;           // 0 or 1
  int w = (t & 127) * 4;       // 0..508
  float4 acc[32];
#pragma unroll
  for (int o = 0; o < 32; ++o) acc[o] = make_float4(0.f, 0.f, 0.f, 0.f);
  const float* src = w1 + ((size_t)b * 32 * 512 + h0) * 512 + 4 * t;  // 4t = hoff*512 + w
#pragma unroll 4
  for (int i = 0; i < 32; ++i) {
    float4 x = *(const float4*)(src + (size_t)i * 262144);
    const float* wp = wl + i * 32;
#pragma unroll
    for (int o = 0; o < 32; ++o) {
      acc[o].x += wp[o] * x.x;
      acc[o].y += wp[o] * x.y;
      acc[o].z += wp[o] * x.z;
      acc[o].w += wp[o] * x.w;
    }
  }
  int h = h0 + hoff;
#pragma unroll
  for (int o = 0; o < 32; ++o) {
    float cf = cterm[((size_t)b * 32 + o) * 512 + h];
    float4 rt = *(const float4*)(rterm + ((size_t)b * 32 + o) * 512 + w);
    float4 res = make_float4(acc[o].x + rt.x + cf, acc[o].y + rt.y + cf,
                             acc[o].z + rt.z + cf, acc[o].w + rt.w + cf);
    *(float4*)(out + (size_t)OUT_ZW1 + (((size_t)b * 32 + o) * 512 + h) * 512 + w) = res;
  }
}

extern "C" void kernel_launch(void* const* d_in, const int* in_sizes, int n_in,
                              void* d_out, int out_size, void* d_ws, size_t ws_size,
                              hipStream_t stream) {
  const float* w0 = (const float*)d_in[0];
  const float* w1 = (const float*)d_in[1];
  const float* w2 = (const float*)d_in[2];
  const float* b0 = (const float*)d_in[3];
  const float* b1 = (const float*)d_in[4];
  const float* b2 = (const float*)d_in[5];
  const float* W_w0_rpt = (const float*)d_in[6];
  const float* B_w0_rpt = (const float*)d_in[7];
  const float* W_w0_rc = (const float*)d_in[8];
  const float* B_w0_rc = (const float*)d_in[9];
  const float* W_b0 = (const float*)d_in[10];
  const float* B_b0 = (const float*)d_in[11];
  const float* W_b0_rc = (const float*)d_in[12];
  const float* B_b0_rc = (const float*)d_in[13];
  const float* W_l1 = (const float*)d_in[14];
  const float* B_l1 = (const float*)d_in[15];
  const float* W_l1_rc = (const float*)d_in[16];
  const float* B_l1_rc = (const float*)d_in[17];
  const float* W_l1_r = (const float*)d_in[18];
  const float* B_l1_r = (const float*)d_in[19];
  const float* W_l1_c = (const float*)d_in[20];
  const float* B_l1_c = (const float*)d_in[21];
  const float* W_bias1 = (const float*)d_in[22];
  const float* B_bias1 = (const float*)d_in[23];
  const float* W_bias1_rc = (const float*)d_in[24];
  const float* B_bias1_rc = (const float*)d_in[25];
  const float* W_fin_cpt = (const float*)d_in[26];
  const float* B_fin_cpt = (const float*)d_in[27];
  const float* W_fin_rc = (const float*)d_in[28];
  const float* B_fin_rc = (const float*)d_in[29];
  const float* W_bfin_rc = (const float*)d_in[30];
  const float* B_bfin_rc = (const float*)d_in[31];
  float* ws = (float*)d_ws;
  float* out = (float*)d_out;

  kprep<<<dim3(814), 256, 0, stream>>>(w0, W_l1, ws);

  kstats2<<<dim3(1280), 256, 0, stream>>>(w0, w2, b0, b1, b2, w1, ws + WS_CM0,
                                          ws + WS_RM2, ws + WS_CM2, ws + WS_RM1,
                                          ws + WS_CM1, ws + WS_RC);

  krcgemm<<<dim3(8 * 312), 256, 0, stream>>>(
      ws + WS_RC, W_w0_rc, B_w0_rc, W_b0_rc, B_b0_rc, W_l1_rc, B_l1_rc, W_bias1_rc,
      B_bias1_rc, W_fin_rc, B_fin_rc, W_bfin_rc, B_bfin_rc, ws + WS_TW0, ws + WS_TB0,
      ws + WS_TL1, ws + WS_TBIAS1, ws + WS_TFIN, out + OUT_U2);

  kbig<<<dim3(1856), 256, 0, stream>>>(
      ws + WS_RM1, ws + WS_CM0, b0, ws + WS_W0T, W_l1_r, B_l1_r, ws + WS_RTERM,
      ws + WS_CM1, b1, ws + WS_RM2, w2, W_l1_c, B_l1_c, B_l1, ws + WS_TL1, W_bias1,
      B_bias1, ws + WS_TBIAS1, ws + WS_CTERM, out + OUT_U1,
      W_w0_rpt, B_w0_rpt, W_b0, B_b0, ws + WS_TW0, ws + WS_TB0,
      W_fin_cpt, B_fin_cpt, ws + WS_TFIN, out);

  kzw1<<<dim3(256, 8), 256, 0, stream>>>(w1, ws + WS_WT_L1, ws + WS_RTERM, ws + WS_CTERM,
                                         out);
  (void)in_sizes; (void)n_in; (void)out_size; (void)ws_size;
}